// Round 3
// baseline (542.150 us; speedup 1.0000x reference)
//
#include <hip/hip_runtime.h>
#include <math.h>

// VQVAE graph-transformer forward, fp32 throughout.
// B=4 N=128 DIM=256 HEADS=8 DH=64 EDGE=64 DEPTH=2 K=512 INNER=512
// ekv = e@w_ekv never materialized (qe pre-contraction + ae post-contraction).
// R3: head-fused attention (1 block per (b,i), e staged once for all 8 heads),
//     qe + rope folded into attn, q/kv fused into one dual-weight GEMM.

#define DEV __device__ __forceinline__

constexpr int Bn = 4, Nn = 128, DIMn = 256, HEADSn = 8, DHn = 64, EDGEn = 64,
              DEPTHn = 2, Kn = 512, INNERn = 512;
constexpr int QKVW = 1536;  // row stride of fused [q|k|v] buffer

DEV float wave_reduce_sum(float v) {
#pragma unroll
  for (int m = 32; m >= 1; m >>= 1) v += __shfl_xor(v, m);
  return v;
}

DEV float block_reduce_sum_256(float v, float* red) {
  v = wave_reduce_sum(v);
  int tid = threadIdx.x;
  if ((tid & 63) == 0) red[tid >> 6] = v;
  __syncthreads();
  v = red[0] + red[1] + red[2] + red[3];
  __syncthreads();
  return v;
}

// ---------------------------------------------------------------------------
// Edge LayerNorm: edges (B,EDGE,N,N) -> e stored as [b][i][c][j].
__global__ __launch_bounds__(256) void edge_ln_kernel(
    const float* __restrict__ edges, const float* __restrict__ g,
    const float* __restrict__ bta, float* __restrict__ e) {
  int t = blockIdx.x * 256 + threadIdx.x;
  int j = t & 127;
  int i = (t >> 7) & 127;
  int b = t >> 14;
  const float* src = edges + (size_t)b * EDGEn * Nn * Nn + i * Nn + j;
  float vals[EDGEn];
  float s = 0.f;
#pragma unroll
  for (int c = 0; c < EDGEn; ++c) {
    float x = src[(size_t)c * (Nn * Nn)];
    vals[c] = x;
    s += x;
  }
  float m = s * (1.0f / 64.0f);
  float s2 = 0.f;
#pragma unroll
  for (int c = 0; c < EDGEn; ++c) {
    float d = vals[c] - m;
    s2 += d * d;
  }
  float inv = 1.f / sqrtf(s2 * (1.0f / 64.0f) + 1e-5f);
  float* dst = e + ((size_t)(b * Nn + i) * EDGEn) * Nn + j;
#pragma unroll
  for (int c = 0; c < EDGEn; ++c)
    dst[(size_t)c * Nn] = (vals[c] - m) * inv * g[c] + bta[c];
}

// ---------------------------------------------------------------------------
__global__ void rope_table_kernel(float* __restrict__ cost,
                                  float* __restrict__ sint) {
  int t = blockIdx.x * 256 + threadIdx.x;
  if (t >= Nn * 32) return;
  int n = t >> 5, p = t & 31;
  float inv = powf(10000.f, -(float)(2 * p) / 64.f);
  float fr = (float)n * inv;
  cost[t] = cosf(fr);
  sint[t] = sinf(fr);
}

// ---------------------------------------------------------------------------
// Row LayerNorm over DIM=256 (layer-0 entry only).
__global__ __launch_bounds__(256) void ln_kernel(const float* __restrict__ x,
                                                 const float* __restrict__ g,
                                                 const float* __restrict__ b,
                                                 float* __restrict__ y) {
  __shared__ float red[4];
  int row = blockIdx.x, tid = threadIdx.x;
  float v = x[(size_t)row * DIMn + tid];
  float m = block_reduce_sum_256(v, red) * (1.0f / 256.0f);
  float d = v - m;
  float var = block_reduce_sum_256(d * d, red) * (1.0f / 256.0f);
  float inv = 1.f / sqrtf(var + 1e-5f);
  y[(size_t)row * DIMn + tid] = d * inv * g[tid] + b[tid];
}

// ---------------------------------------------------------------------------
// fp32 GEMM, dual-weight variant: output col cc takes W1/b1 if cc<N1 else
// W2/b2 at (cc-N1). C row stride = Ntot. 32x64 tile, BK=32, 2x4 microtile.
// act: 0 none, 1 exact gelu.
__global__ __launch_bounds__(256) void gemm_kernel(
    const float* __restrict__ A, const float* __restrict__ W1, int N1,
    const float* __restrict__ b1, const float* __restrict__ W2, int N2,
    const float* __restrict__ b2, float* __restrict__ C, int M, int Ntot,
    int K, int act) {
  __shared__ float As[32][34];
  __shared__ __align__(16) float Bs[32][68];
  int tid = threadIdx.x;
  int bx = blockIdx.x, by = blockIdx.y;
  int tx = tid & 15, ty = tid >> 4;
  int arow = tid >> 3, acol = (tid & 7) << 2;
  int brow = tid >> 4, bcol = (tid & 15) << 2;
  int col0 = bx * 64;
  const float* W = W1;
  const float* bias = b1;
  int Nw = N1, wcol = col0;
  if (col0 >= N1) {
    W = W2;
    bias = b2;
    Nw = N2;
    wcol = col0 - N1;
  }
  float acc[2][4] = {};
  for (int k0 = 0; k0 < K; k0 += 32) {
    float4 a4 = *(const float4*)(A + (size_t)(by * 32 + arow) * K + k0 + acol);
    As[acol + 0][arow] = a4.x;
    As[acol + 1][arow] = a4.y;
    As[acol + 2][arow] = a4.z;
    As[acol + 3][arow] = a4.w;
    float4 b4 = *(const float4*)(W + (size_t)(k0 + brow) * Nw + wcol + bcol);
    *(float4*)&Bs[brow][bcol] = b4;
    float4 b4b =
        *(const float4*)(W + (size_t)(k0 + brow + 16) * Nw + wcol + bcol);
    *(float4*)&Bs[brow + 16][bcol] = b4b;
    __syncthreads();
#pragma unroll
    for (int kk = 0; kk < 32; ++kk) {
      float2 av = *(const float2*)&As[kk][ty * 2];
      float4 bv = *(const float4*)&Bs[kk][tx * 4];
      acc[0][0] += av.x * bv.x;
      acc[0][1] += av.x * bv.y;
      acc[0][2] += av.x * bv.z;
      acc[0][3] += av.x * bv.w;
      acc[1][0] += av.y * bv.x;
      acc[1][1] += av.y * bv.y;
      acc[1][2] += av.y * bv.z;
      acc[1][3] += av.y * bv.w;
    }
    __syncthreads();
  }
  int ccol = wcol + tx * 4;
#pragma unroll
  for (int u = 0; u < 2; ++u) {
    int r = by * 32 + ty * 2 + u;
    float o[4];
#pragma unroll
    for (int w = 0; w < 4; ++w) o[w] = acc[u][w] + bias[ccol + w];
    if (act == 1) {
#pragma unroll
      for (int w = 0; w < 4; ++w)
        o[w] = 0.5f * o[w] * (1.f + erff(o[w] * 0.70710678118654752f));
    }
    float4 o4 = {o[0], o[1], o[2], o[3]};
    *(float4*)(C + (size_t)r * Ntot + col0 + tx * 4) = o4;
  }
}

// ---------------------------------------------------------------------------
// Head-fused attention: one 256-thread block per (b,i). All 8 heads.
// qkv rows: [q(512) | k(512) | v(512)], raw (rope applied here on load).
// qe computed in-block; e-slice staged once and reused by all heads.
__global__ __launch_bounds__(256) void attn_kernel(
    const float* __restrict__ qkv, const float* __restrict__ e,
    const float* __restrict__ wek, const float* __restrict__ bek,
    const float* __restrict__ cost, const float* __restrict__ sint,
    float* __restrict__ attn_out) {
  __shared__ __align__(16) float qs[512];    // rotated q, all heads
  __shared__ float qes[8 * 64];              // qe[h][c]
  __shared__ float es[64 * 129];             // e [c][j], pad->conflict-free
  __shared__ float simb[8 * 128];            // sim/att [h][j]
  __shared__ float aef[8 * 64];              // ae [h][c]
  int blk = blockIdx.x;
  int i = blk & 127, b = blk >> 7;
  int tid = threadIdx.x;
  int row = b * 128 + i;

  // --- P0: stage rotated q (float2 per thread) + e-slice
  {
    int d2 = tid * 2;
    float2 qv = *(const float2*)(qkv + (size_t)row * QKVW + d2);
    int p = (d2 & 63) >> 1;
    float c = cost[i * 32 + p], s = sint[i * 32 + p];
    qs[d2] = qv.x * c - qv.y * s;
    qs[d2 + 1] = qv.y * c + qv.x * s;
  }
  {
    const float* ebase = e + ((size_t)row * 64) * 128;
    for (int f = tid; f < 2048; f += 256) {
      int c = f >> 5, j4 = (f & 31) << 2;
      float4 v4 = *(const float4*)(ebase + (size_t)c * 128 + j4);
      es[c * 129 + j4 + 0] = v4.x;
      es[c * 129 + j4 + 1] = v4.y;
      es[c * 129 + j4 + 2] = v4.z;
      es[c * 129 + j4 + 3] = v4.w;
    }
  }
  __syncthreads();

  // --- P0b: qe[h][c] = sum_d qs[h*64+d] * wek[c*512 + h*64 + d]
  {
    int h = tid >> 5, l = tid & 31;
    float acc0 = 0.f, acc1 = 0.f;
    const float* qh = qs + h * 64;
    const float* w0 = wek + (size_t)(2 * l) * INNERn + h * 64;
    const float* w1 = w0 + INNERn;
#pragma unroll
    for (int d4 = 0; d4 < 16; ++d4) {
      float4 q4 = *(const float4*)(qh + d4 * 4);
      float4 wa = *(const float4*)(w0 + d4 * 4);
      float4 wb = *(const float4*)(w1 + d4 * 4);
      acc0 += q4.x * wa.x + q4.y * wa.y + q4.z * wa.z + q4.w * wa.w;
      acc1 += q4.x * wb.x + q4.y * wb.y + q4.z * wb.z + q4.w * wb.w;
    }
    qes[h * 64 + 2 * l] = acc0;
    qes[h * 64 + 2 * l + 1] = acc1;
  }
  __syncthreads();

  // --- P1: sim[h][j] for h in {h2*4..h2*4+3}, j = tid&127
  {
    int h2 = tid >> 7, j = tid & 127;
#pragma unroll
    for (int hh = 0; hh < 4; ++hh) {
      int h = h2 * 4 + hh;
      const float4* krow =
          (const float4*)(qkv + (size_t)(b * 128 + j) * QKVW + 512 + h * 64);
      const float4* q4p = (const float4*)(qs + h * 64);
      float s = 0.f;
#pragma unroll
      for (int t4 = 0; t4 < 16; ++t4) {
        float4 k4 = krow[t4];
        int p0 = 2 * t4;
        float c0 = cost[j * 32 + p0], s0 = sint[j * 32 + p0];
        float c1 = cost[j * 32 + p0 + 1], s1 = sint[j * 32 + p0 + 1];
        float kr0 = k4.x * c0 - k4.y * s0;
        float kr1 = k4.y * c0 + k4.x * s0;
        float kr2 = k4.z * c1 - k4.w * s1;
        float kr3 = k4.w * c1 + k4.z * s1;
        float4 q4 = q4p[t4];
        s += q4.x * kr0 + q4.y * kr1 + q4.z * kr2 + q4.w * kr3;
      }
      const float* qeh = qes + h * 64;
#pragma unroll
      for (int c = 0; c < 64; ++c) s += qeh[c] * es[c * 129 + j];
      simb[h * 128 + j] = s * 0.125f;
    }
  }
  __syncthreads();

  // --- P2: softmax per h over 128 (32-lane group per h, 4 j each)
  {
    int h = tid >> 5, l = tid & 31;
    float s0 = simb[h * 128 + l];
    float s1 = simb[h * 128 + l + 32];
    float s2 = simb[h * 128 + l + 64];
    float s3 = simb[h * 128 + l + 96];
    float mx = fmaxf(fmaxf(s0, s1), fmaxf(s2, s3));
#pragma unroll
    for (int m = 16; m >= 1; m >>= 1) mx = fmaxf(mx, __shfl_xor(mx, m));
    float p0 = expf(s0 - mx), p1 = expf(s1 - mx), p2 = expf(s2 - mx),
          p3 = expf(s3 - mx);
    float sm = p0 + p1 + p2 + p3;
#pragma unroll
    for (int m = 16; m >= 1; m >>= 1) sm += __shfl_xor(sm, m);
    float inv = 1.f / sm;
    simb[h * 128 + l] = p0 * inv;
    simb[h * 128 + l + 32] = p1 * inv;
    simb[h * 128 + l + 64] = p2 * inv;
    simb[h * 128 + l + 96] = p3 * inv;
  }
  __syncthreads();

  // --- P3: av[h][d], ae[h][c] ; d,c = 2l, 2l+1
  int h = tid >> 5, l = tid & 31;
  float av0 = 0.f, av1 = 0.f, ae0 = 0.f, ae1 = 0.f;
  {
    const float* vb = qkv + (size_t)(b * 128) * QKVW + 1024 + h * 64 + 2 * l;
    const float* e0 = es + (2 * l) * 129;
    const float* e1 = es + (2 * l + 1) * 129;
    const float* at = simb + h * 128;
#pragma unroll 4
    for (int j = 0; j < 128; ++j) {
      float a = at[j];
      float2 v2 = *(const float2*)(vb + (size_t)j * QKVW);
      av0 += a * v2.x;
      av1 += a * v2.y;
      ae0 += a * e0[j];
      ae1 += a * e1[j];
    }
    aef[h * 64 + 2 * l] = ae0;
    aef[h * 64 + 2 * l + 1] = ae1;
  }
  __syncthreads();

  // --- P4: out[h][d] = av + bek + sum_c aef[h][c] * wek[c][h*64+d]
  {
    int d0 = 2 * l;
    float2 bk = *(const float2*)(bek + h * 64 + d0);
    float o0 = av0 + bk.x, o1 = av1 + bk.y;
    const float* af = aef + h * 64;
    const float* wb = wek + h * 64 + d0;
#pragma unroll 8
    for (int c = 0; c < 64; ++c) {
      float a = af[c];
      float2 w2 = *(const float2*)(wb + (size_t)c * INNERn);
      o0 += a * w2.x;
      o1 += a * w2.y;
    }
    float2 o = {o0, o1};
    *(float2*)(attn_out + (size_t)row * INNERn + h * 64 + d0) = o;
  }
}

// ---------------------------------------------------------------------------
// Gated residual + optional fused LayerNorm of the result.
__global__ __launch_bounds__(256) void gate_ln_kernel(
    const float* __restrict__ x, float* __restrict__ nodes,
    const float* __restrict__ gw, const float* __restrict__ lng,
    const float* __restrict__ lnb, float* __restrict__ xln) {
  __shared__ float red[4];
  int row = blockIdx.x, tid = threadIdx.x;
  float xv = x[(size_t)row * DIMn + tid];
  float rv = nodes[(size_t)row * DIMn + tid];
  float pv =
      xv * gw[tid] + rv * gw[DIMn + tid] + (xv - rv) * gw[2 * DIMn + tid];
  float ssum = block_reduce_sum_256(pv, red);
  float gsig = 1.f / (1.f + expf(-ssum));
  float nv = xv * gsig + rv * (1.f - gsig);
  nodes[(size_t)row * DIMn + tid] = nv;
  if (lng) {
    float m = block_reduce_sum_256(nv, red) * (1.0f / 256.0f);
    float d = nv - m;
    float var = block_reduce_sum_256(d * d, red) * (1.0f / 256.0f);
    float inv = 1.f / sqrtf(var + 1e-5f);
    xln[(size_t)row * DIMn + tid] = d * inv * lng[tid] + lnb[tid];
  }
}

// ---------------------------------------------------------------------------
// VQ nearest neighbor: thread-per-codebook-entry, 4 rows per block.
__global__ __launch_bounds__(256) void vq_kernel(
    const float* __restrict__ nodes, const float* __restrict__ codebook,
    float* __restrict__ out) {
  __shared__ __align__(16) float zs[4 * 256];
  __shared__ float wval[4][4];
  __shared__ int widx[4][4];
  __shared__ int fidx[4];
  int row0 = blockIdx.x * 4;
  int tid = threadIdx.x;
  for (int f = tid; f < 1024; f += 256) zs[f] = nodes[(size_t)row0 * DIMn + f];
  __syncthreads();
  int k1 = tid, k2 = tid + 256;
  const float4* c1p = (const float4*)(codebook + (size_t)k1 * DIMn);
  const float4* c2p = (const float4*)(codebook + (size_t)k2 * DIMn);
  float dot[4][2] = {};
  float cc0 = 0.f, cc1 = 0.f;
#pragma unroll 8
  for (int d4 = 0; d4 < 64; ++d4) {
    float4 c1 = c1p[d4], c2 = c2p[d4];
    cc0 += c1.x * c1.x + c1.y * c1.y + c1.z * c1.z + c1.w * c1.w;
    cc1 += c2.x * c2.x + c2.y * c2.y + c2.z * c2.z + c2.w * c2.w;
#pragma unroll
    for (int r = 0; r < 4; ++r) {
      float4 z = *(const float4*)&zs[r * 256 + d4 * 4];
      dot[r][0] += c1.x * z.x + c1.y * z.y + c1.z * z.z + c1.w * z.w;
      dot[r][1] += c2.x * z.x + c2.y * z.y + c2.z * z.z + c2.w * z.w;
    }
  }
  int lane = tid & 63, w = tid >> 6;
#pragma unroll
  for (int r = 0; r < 4; ++r) {
    float bv = cc0 - 2.f * dot[r][0];
    int bi = k1;
    float v2 = cc1 - 2.f * dot[r][1];
    if (v2 < bv) {
      bv = v2;
      bi = k2;
    }
#pragma unroll
    for (int m = 32; m >= 1; m >>= 1) {
      float ov = __shfl_xor(bv, m);
      int oi = __shfl_xor(bi, m);
      if (ov < bv || (ov == bv && oi < bi)) {
        bv = ov;
        bi = oi;
      }
    }
    if (lane == 0) {
      wval[r][w] = bv;
      widx[r][w] = bi;
    }
  }
  __syncthreads();
  if (tid < 4) {
    float bb = wval[tid][0];
    int bi = widx[tid][0];
    for (int t = 1; t < 4; ++t)
      if (wval[tid][t] < bb || (wval[tid][t] == bb && widx[tid][t] < bi)) {
        bb = wval[tid][t];
        bi = widx[tid][t];
      }
    fidx[tid] = bi;
  }
  __syncthreads();
  for (int f = tid; f < 1024; f += 256) {
    int r = f >> 8, d = f & 255;
    float zv = zs[f];
    float zq = codebook[(size_t)fidx[r] * DIMn + d];
    out[(size_t)(row0 + r) * DIMn + d] = zv + (zq - zv);
  }
}

// ---------------------------------------------------------------------------
extern "C" void kernel_launch(void* const* d_in, const int* in_sizes, int n_in,
                              void* d_out, int out_size, void* d_ws,
                              size_t ws_size, hipStream_t stream) {
  const float* nodes_in = (const float*)d_in[0];
  const float* edges = (const float*)d_in[1];
  const float* edge_ln_g = (const float*)d_in[2];
  const float* edge_ln_b = (const float*)d_in[3];
  const float* ln1_g = (const float*)d_in[4];
  const float* ln1_b = (const float*)d_in[5];
  const float* w_exp = (const float*)d_in[6];
  const float* b_exp = (const float*)d_in[7];
  const float* w_q = (const float*)d_in[8];
  const float* b_q = (const float*)d_in[9];
  const float* w_kv = (const float*)d_in[10];
  const float* b_kv = (const float*)d_in[11];
  const float* w_ekv = (const float*)d_in[12];
  const float* b_ekv = (const float*)d_in[13];
  const float* w_out = (const float*)d_in[14];
  const float* b_out = (const float*)d_in[15];
  const float* gate1_w = (const float*)d_in[16];
  const float* ln2_g = (const float*)d_in[17];
  const float* ln2_b = (const float*)d_in[18];
  const float* w_ff1 = (const float*)d_in[19];
  const float* b_ff1 = (const float*)d_in[20];
  const float* w_ff2 = (const float*)d_in[21];
  const float* b_ff2 = (const float*)d_in[22];
  const float* gate2_w = (const float*)d_in[23];
  const float* codebook = (const float*)d_in[24];

  float* ws = (float*)d_ws;
  float* e_buf = ws;                 // 4194304
  float* cost = e_buf + 4194304;     // 4096
  float* sint = cost + 4096;         // 4096
  float* nodes = sint + 4096;        // 131072
  float* xln = nodes + 131072;       // 131072
  float* xe = xln + 131072;          // 262144
  float* qkvb = xe + 262144;         // 786432 ([q|k|v] rows of 1536)
  float* attnb = qkvb + 786432;      // 262144
  float* proj = attnb + 262144;      // 131072
  float* ff1 = proj + 131072;        // 524288

  hipMemcpyAsync(nodes, nodes_in, sizeof(float) * Bn * Nn * DIMn,
                 hipMemcpyDeviceToDevice, stream);
  edge_ln_kernel<<<256, 256, 0, stream>>>(edges, edge_ln_g, edge_ln_b, e_buf);
  rope_table_kernel<<<16, 256, 0, stream>>>(cost, sint);

  for (int l = 0; l < DEPTHn; ++l) {
    if (l == 0) ln_kernel<<<512, 256, 0, stream>>>(nodes, ln1_g, ln1_b, xln);
    // exp: xln(512x256) @ w_exp -> xe (512x512)
    gemm_kernel<<<dim3(8, 16), 256, 0, stream>>>(
        xln, w_exp + l * 256 * 512, 512, b_exp + l * 512, nullptr, 0, nullptr,
        xe, 512, 512, 256, 0);
    // fused q|kv: xe(512x512) @ [w_q | w_kv] -> qkvb (512x1536)
    gemm_kernel<<<dim3(24, 16), 256, 0, stream>>>(
        xe, w_q + l * 512 * 512, 512, b_q + l * 512, w_kv + l * 512 * 1024,
        1024, b_kv + l * 1024, qkvb, 512, QKVW, 512, 0);
    // head-fused attention (rope + qe inside)
    attn_kernel<<<512, 256, 0, stream>>>(qkvb, e_buf, w_ekv + l * 64 * 512,
                                         b_ekv + l * 512, cost, sint, attnb);
    // out-proj
    gemm_kernel<<<dim3(4, 16), 256, 0, stream>>>(
        attnb, w_out + l * 512 * 256, 256, b_out + l * 256, nullptr, 0,
        nullptr, proj, 512, 256, 512, 0);
    gate_ln_kernel<<<512, 256, 0, stream>>>(proj, nodes, gate1_w + l * 768,
                                            ln2_g + l * 256, ln2_b + l * 256,
                                            xln);
    gemm_kernel<<<dim3(16, 16), 256, 0, stream>>>(
        xln, w_ff1 + l * 256 * 1024, 1024, b_ff1 + l * 1024, nullptr, 0,
        nullptr, ff1, 512, 1024, 256, 1);
    gemm_kernel<<<dim3(4, 16), 256, 0, stream>>>(
        ff1, w_ff2 + l * 1024 * 256, 256, b_ff2 + l * 256, nullptr, 0, nullptr,
        proj, 512, 256, 1024, 0);
    const float* nlng = (l + 1 < DEPTHn) ? ln1_g + (l + 1) * 256 : nullptr;
    const float* nlnb = (l + 1 < DEPTHn) ? ln1_b + (l + 1) * 256 : nullptr;
    gate_ln_kernel<<<512, 256, 0, stream>>>(proj, nodes, gate2_w + l * 768,
                                            nlng, nlnb, xln);
  }
  vq_kernel<<<128, 256, 0, stream>>>(nodes, codebook, (float*)d_out);
}

// Round 4
// 471.700 us; speedup vs baseline: 1.1494x; 1.1494x over previous
//
#include <hip/hip_runtime.h>
#include <math.h>

// VQVAE graph-transformer forward, fp32 throughout.
// B=4 N=128 DIM=256 HEADS=8 DH=64 EDGE=64 DEPTH=2 K=512 INNER=512
// ekv = e@w_ekv never materialized. R4:
//  - attn: (b,h,i-quad) blocks, all-coalesced via kT / e / eT layouts,
//    half-wave softmax, [av|ae] output; epilogue folded into out-proj GEMM
//    via precomputed W2 = blockdiag(wek) @ w_out and b_out2 = b_out+bek@w_out.
//  - qkv GEMM epilogue applies rope to q,k and scatters kT via LDS transpose.

#define DEV __device__ __forceinline__

constexpr int Bn = 4, Nn = 128, DIMn = 256, HEADSn = 8, DHn = 64, EDGEn = 64,
              DEPTHn = 2, Kn = 512, INNERn = 512;
constexpr int QKVW = 1536;

DEV float wave_reduce_sum(float v) {
#pragma unroll
  for (int m = 32; m >= 1; m >>= 1) v += __shfl_xor(v, m);
  return v;
}

DEV float block_reduce_sum_256(float v, float* red) {
  v = wave_reduce_sum(v);
  int tid = threadIdx.x;
  if ((tid & 63) == 0) red[tid >> 6] = v;
  __syncthreads();
  v = red[0] + red[1] + red[2] + red[3];
  __syncthreads();
  return v;
}

// ---------------------------------------------------------------------------
// Edge LayerNorm -> e[b][i][c][j]  AND  eT[b][i][j][c]. Block per (b,i).
__global__ __launch_bounds__(128) void edge_ln_kernel(
    const float* __restrict__ edges, const float* __restrict__ g,
    const float* __restrict__ bta, float* __restrict__ e,
    float* __restrict__ eT) {
  __shared__ float ets[128 * 65];
  int blk = blockIdx.x;  // b*128 + i
  int i = blk & 127, b = blk >> 7;
  int j = threadIdx.x;
  const float* src = edges + (size_t)b * EDGEn * Nn * Nn + i * Nn + j;
  float vals[EDGEn];
  float s = 0.f;
#pragma unroll
  for (int c = 0; c < EDGEn; ++c) {
    float x = src[(size_t)c * (Nn * Nn)];
    vals[c] = x;
    s += x;
  }
  float m = s * (1.0f / 64.0f);
  float s2 = 0.f;
#pragma unroll
  for (int c = 0; c < EDGEn; ++c) {
    float d = vals[c] - m;
    s2 += d * d;
  }
  float inv = 1.f / sqrtf(s2 * (1.0f / 64.0f) + 1e-5f);
  float* dst = e + ((size_t)(b * Nn + i) * EDGEn) * Nn + j;
#pragma unroll
  for (int c = 0; c < EDGEn; ++c) {
    float o = (vals[c] - m) * inv * g[c] + bta[c];
    dst[(size_t)c * Nn] = o;
    ets[j * 65 + c] = o;
  }
  __syncthreads();
  float* dstT = eT + ((size_t)(b * Nn + i) * Nn) * EDGEn;
#pragma unroll
  for (int it = 0; it < 16; ++it) {
    int f4 = it * 128 + j;  // 0..2047 float4s
    int jj = f4 >> 4, c4 = (f4 & 15) << 2;
    float4 o4 = {ets[jj * 65 + c4], ets[jj * 65 + c4 + 1],
                 ets[jj * 65 + c4 + 2], ets[jj * 65 + c4 + 3]};
    *(float4*)(dstT + (size_t)jj * EDGEn + c4) = o4;
  }
}

// ---------------------------------------------------------------------------
__global__ void rope_table_kernel(float* __restrict__ cost,
                                  float* __restrict__ sint) {
  int t = blockIdx.x * 256 + threadIdx.x;
  if (t >= Nn * 32) return;
  int n = t >> 5, p = t & 31;
  float inv = powf(10000.f, -(float)(2 * p) / 64.f);
  float fr = (float)n * inv;
  cost[t] = cosf(fr);
  sint[t] = sinf(fr);
}

// ---------------------------------------------------------------------------
// Fold kernel: W2[l][h*64+c][n] = sum_d wek[l][c][h64+d] * w_out[l][h64+d][n]
// and b_out2[l][n] = b_out[l][n] + sum_k bek[l][k]*w_out[l][k][n].
__global__ __launch_bounds__(256) void wfold_kernel(
    const float* __restrict__ wek, const float* __restrict__ w_out,
    const float* __restrict__ bek, const float* __restrict__ b_out,
    float* __restrict__ W2, float* __restrict__ b_out2) {
  int blk = blockIdx.x;
  int tid = threadIdx.x;
  if (blk < 64) {
    int l = blk >> 5, h = (blk >> 2) & 7, nt = blk & 3;
    __shared__ float As[64 * 65];  // [c][d]
    __shared__ float Bs[64 * 68];  // [d][n]
    const float* wekl = wek + (size_t)l * 64 * 512 + h * 64;
    const float* woutl =
        w_out + (size_t)l * 512 * 256 + (size_t)(h * 64) * 256 + nt * 64;
    for (int f = tid; f < 1024; f += 256) {
      int c = f >> 4, d4 = (f & 15) << 2;
      float4 w4 = *(const float4*)(wekl + (size_t)c * 512 + d4);
      As[c * 65 + d4 + 0] = w4.x;
      As[c * 65 + d4 + 1] = w4.y;
      As[c * 65 + d4 + 2] = w4.z;
      As[c * 65 + d4 + 3] = w4.w;
    }
    for (int f = tid; f < 1024; f += 256) {
      int d = f >> 4, n4 = (f & 15) << 2;
      float4 w4 = *(const float4*)(woutl + (size_t)d * 256 + n4);
      Bs[d * 68 + n4 + 0] = w4.x;
      Bs[d * 68 + n4 + 1] = w4.y;
      Bs[d * 68 + n4 + 2] = w4.z;
      Bs[d * 68 + n4 + 3] = w4.w;
    }
    __syncthreads();
    int tx = tid & 15, ty = tid >> 4;
    float acc[4][4] = {};
    for (int d = 0; d < 64; ++d) {
      float4 bv = *(const float4*)&Bs[d * 68 + tx * 4];
#pragma unroll
      for (int u = 0; u < 4; ++u) {
        float a = As[(ty * 4 + u) * 65 + d];
        acc[u][0] += a * bv.x;
        acc[u][1] += a * bv.y;
        acc[u][2] += a * bv.z;
        acc[u][3] += a * bv.w;
      }
    }
#pragma unroll
    for (int u = 0; u < 4; ++u) {
      float4 o = {acc[u][0], acc[u][1], acc[u][2], acc[u][3]};
      *(float4*)(W2 + (size_t)l * 512 * 256 +
                 (size_t)(h * 64 + ty * 4 + u) * 256 + nt * 64 + tx * 4) = o;
    }
  } else {
    int t = blk - 64;
    int l = t >> 2, nt = t & 3;
    __shared__ float part[256];
    int nn = tid & 63, kq = tid >> 6;
    const float* wcol = w_out + (size_t)l * 512 * 256 + nt * 64 + nn;
    float acc = 0.f;
    for (int k = kq * 128; k < kq * 128 + 128; ++k)
      acc += bek[l * 512 + k] * wcol[(size_t)k * 256];
    part[tid] = acc;
    __syncthreads();
    if (tid < 64)
      b_out2[l * 256 + nt * 64 + nn] =
          b_out[l * 256 + nt * 64 + nn] + part[nn] + part[64 + nn] +
          part[128 + nn] + part[192 + nn];
  }
}

// ---------------------------------------------------------------------------
// Row LayerNorm over DIM=256 (layer-0 entry only).
__global__ __launch_bounds__(256) void ln_kernel(const float* __restrict__ x,
                                                 const float* __restrict__ g,
                                                 const float* __restrict__ b,
                                                 float* __restrict__ y) {
  __shared__ float red[4];
  int row = blockIdx.x, tid = threadIdx.x;
  float v = x[(size_t)row * DIMn + tid];
  float m = block_reduce_sum_256(v, red) * (1.0f / 256.0f);
  float d = v - m;
  float var = block_reduce_sum_256(d * d, red) * (1.0f / 256.0f);
  float inv = 1.f / sqrtf(var + 1e-5f);
  y[(size_t)row * DIMn + tid] = d * inv * g[tid] + b[tid];
}

// ---------------------------------------------------------------------------
// fp32 GEMM, 32x64 tile, BK=32, 2x4 microtile.
// Dual-N (W1/N1/b1 then W2n/N2/b2 at col>=N1), dual-K (rows>=Ksplit from Wkb).
// act: 0 none, 1 exact gelu, 4 qkv mode (rope q/k; k scattered to kT, no C).
__global__ __launch_bounds__(256) void gemm_kernel(
    const float* __restrict__ A, const float* __restrict__ W1, int N1,
    const float* __restrict__ b1, const float* __restrict__ W2n, int N2,
    const float* __restrict__ b2, const float* __restrict__ Wkb, int Ksplit,
    float* __restrict__ C, int M, int Ntot, int K, int act,
    const float* __restrict__ cost, const float* __restrict__ sint,
    float* __restrict__ kT) {
  __shared__ float As[32][34];
  __shared__ __align__(16) float Bs[32][68];
  int tid = threadIdx.x;
  int bx = blockIdx.x, by = blockIdx.y;
  int tx = tid & 15, ty = tid >> 4;
  int arow = tid >> 3, acol = (tid & 7) << 2;
  int brow = tid >> 4, bcol = (tid & 15) << 2;
  int col0 = bx * 64;
  const float* W = W1;
  const float* bias = b1;
  int Nw = N1, wcol = col0;
  if (W2n && col0 >= N1) {
    W = W2n;
    bias = b2;
    Nw = N2;
    wcol = col0 - N1;
  }
  float acc[2][4] = {};
  for (int k0 = 0; k0 < K; k0 += 32) {
    float4 a4 = *(const float4*)(A + (size_t)(by * 32 + arow) * K + k0 + acol);
    As[acol + 0][arow] = a4.x;
    As[acol + 1][arow] = a4.y;
    As[acol + 2][arow] = a4.z;
    As[acol + 3][arow] = a4.w;
    int kr0 = k0 + brow, kr1 = k0 + brow + 16;
    const float* w0;
    const float* w1;
    if (Ksplit && kr0 >= Ksplit)
      w0 = Wkb + (size_t)(kr0 - Ksplit) * Nw + wcol + bcol;
    else
      w0 = W + (size_t)kr0 * Nw + wcol + bcol;
    if (Ksplit && kr1 >= Ksplit)
      w1 = Wkb + (size_t)(kr1 - Ksplit) * Nw + wcol + bcol;
    else
      w1 = W + (size_t)kr1 * Nw + wcol + bcol;
    *(float4*)&Bs[brow][bcol] = *(const float4*)w0;
    *(float4*)&Bs[brow + 16][bcol] = *(const float4*)w1;
    __syncthreads();
#pragma unroll
    for (int kk = 0; kk < 32; ++kk) {
      float2 av = *(const float2*)&As[kk][ty * 2];
      float4 bv = *(const float4*)&Bs[kk][tx * 4];
      acc[0][0] += av.x * bv.x;
      acc[0][1] += av.x * bv.y;
      acc[0][2] += av.x * bv.z;
      acc[0][3] += av.x * bv.w;
      acc[1][0] += av.y * bv.x;
      acc[1][1] += av.y * bv.y;
      acc[1][2] += av.y * bv.z;
      acc[1][3] += av.y * bv.w;
    }
    __syncthreads();
  }
  int ccol = wcol + tx * 4;
  bool ksec = (act == 4) && (col0 >= 512) && (col0 < 1024);
  float* trans = (float*)Bs;  // 64*33 floats, reused after K loop
#pragma unroll
  for (int u = 0; u < 2; ++u) {
    int r = by * 32 + ty * 2 + u;
    float o[4];
#pragma unroll
    for (int w = 0; w < 4; ++w) o[w] = acc[u][w] + bias[ccol + w];
    if (act == 1) {
#pragma unroll
      for (int w = 0; w < 4; ++w)
        o[w] = 0.5f * o[w] * (1.f + erff(o[w] * 0.70710678118654752f));
    } else if (act == 4 && col0 < 1024) {  // rope for q and k sections
      int n = r & 127;
      int p0 = (ccol & 63) >> 1;
      float c0 = cost[n * 32 + p0], s0 = sint[n * 32 + p0];
      float c1 = cost[n * 32 + p0 + 1], s1 = sint[n * 32 + p0 + 1];
      float x0 = o[0], x1 = o[1], x2 = o[2], x3 = o[3];
      o[0] = x0 * c0 - x1 * s0;
      o[1] = x1 * c0 + x0 * s0;
      o[2] = x2 * c1 - x3 * s1;
      o[3] = x3 * c1 + x2 * s1;
    }
    if (ksec) {
      int jl = ty * 2 + u;
#pragma unroll
      for (int w = 0; w < 4; ++w) trans[(tx * 4 + w) * 33 + jl] = o[w];
    } else {
      float4 o4 = {o[0], o[1], o[2], o[3]};
      *(float4*)(C + (size_t)r * Ntot + col0 + tx * 4) = o4;
    }
  }
  if (ksec) {
    __syncthreads();
    int h = (col0 - 512) >> 6;
    int bb = (by * 32) >> 7;
#pragma unroll
    for (int q = 0; q < 2; ++q) {
      int f4 = tid * 2 + q;  // 0..511
      int dl = f4 >> 3, j4 = (f4 & 7) << 2;
      int jj = (by * 32 + j4) & 127;
      float4 o4 = {trans[dl * 33 + j4], trans[dl * 33 + j4 + 1],
                   trans[dl * 33 + j4 + 2], trans[dl * 33 + j4 + 3]};
      *(float4*)(kT + ((size_t)(bb * 8 + h) * 64 + dl) * 128 + jj) = o4;
    }
  }
}

// ---------------------------------------------------------------------------
// qe[b,h,i,c] = sum_d q_rot[b,i,h64+d] * wek[c,h64+d]. Block=(b,h,iq of 32 i).
__global__ __launch_bounds__(256) void qe_kernel(const float* __restrict__ qkv,
                                                 const float* __restrict__ wek,
                                                 float* __restrict__ qe) {
  __shared__ float qs[32 * 65];
  __shared__ float ws[64 * 65];
  int blk = blockIdx.x;  // ((b*8+h)*4 + iq)
  int iq = blk & 3;
  int bh = blk >> 2;
  int b = bh >> 3, h = bh & 7;
  int i0 = iq * 32;
  int tid = threadIdx.x;
  for (int f = tid; f < 32 * 64; f += 256) {
    int i = f >> 6, d = f & 63;
    qs[i * 65 + d] = qkv[(size_t)(b * 128 + i0 + i) * QKVW + h * 64 + d];
  }
  for (int f = tid; f < 64 * 64; f += 256) {
    int c = f >> 6, d = f & 63;
    ws[c * 65 + d] = wek[(size_t)c * INNERn + h * 64 + d];
  }
  __syncthreads();
  int c = tid & 63, i2 = tid >> 6;
  for (int ib = 0; ib < 8; ++ib) {
    int i = ib * 4 + i2;
    float acc = 0.f;
#pragma unroll
    for (int d = 0; d < 64; ++d) acc += qs[i * 65 + d] * ws[c * 65 + d];
    qe[((size_t)bh * 128 + i0 + i) * 64 + c] = acc;
  }
}

// ---------------------------------------------------------------------------
// Attention core: block per (b,h,i-quad), 128 threads. Writes [av|ae] rows.
__global__ __launch_bounds__(128) void attn_kernel(
    const float* __restrict__ qkv, const float* __restrict__ e,
    const float* __restrict__ eT, const float* __restrict__ kT,
    const float* __restrict__ qeb, float* __restrict__ attn2) {
  __shared__ __align__(16) float qs[256];
  __shared__ __align__(16) float qes[256];
  __shared__ __align__(16) float att[512];
  __shared__ float avh[512];
  __shared__ float aeh[512];
  int blk = blockIdx.x;  // (b*8+h)*32 + iq
  int iq = blk & 31;
  int bh = blk >> 5;
  int h = bh & 7, b = bh >> 3;
  int i0 = iq * 4;
  int row0 = b * 128 + i0;
  int tid = threadIdx.x;

  // P0: stage rotated q + qe for 4 rows
  for (int f = tid; f < 256; f += 128) {
    int ii = f >> 6, d = f & 63;
    qs[f] = qkv[(size_t)(row0 + ii) * QKVW + h * 64 + d];
    qes[f] = qeb[((size_t)bh * 128 + i0 + ii) * 64 + d];
  }
  __syncthreads();

  // P1: sim. thread = (i2 = tid>>5, j-quad = tid&31)
  int i2 = tid >> 5, j4 = tid & 31;
  float s0 = 0.f, s1 = 0.f, s2 = 0.f, s3 = 0.f;
  {
    const float* ktb = kT + ((size_t)bh * 64) * 128 + j4 * 4;
#pragma unroll
    for (int d4 = 0; d4 < 64; d4 += 4) {
      float4 q4 = *(const float4*)&qs[i2 * 64 + d4];
      float4 k0 = *(const float4*)(ktb + (size_t)(d4 + 0) * 128);
      float4 k1 = *(const float4*)(ktb + (size_t)(d4 + 1) * 128);
      float4 k2 = *(const float4*)(ktb + (size_t)(d4 + 2) * 128);
      float4 k3 = *(const float4*)(ktb + (size_t)(d4 + 3) * 128);
      s0 += q4.x * k0.x + q4.y * k1.x + q4.z * k2.x + q4.w * k3.x;
      s1 += q4.x * k0.y + q4.y * k1.y + q4.z * k2.y + q4.w * k3.y;
      s2 += q4.x * k0.z + q4.y * k1.z + q4.z * k2.z + q4.w * k3.z;
      s3 += q4.x * k0.w + q4.y * k1.w + q4.z * k2.w + q4.w * k3.w;
    }
    const float* eb = e + ((size_t)(row0 + i2) * 64) * 128 + j4 * 4;
#pragma unroll
    for (int c4 = 0; c4 < 64; c4 += 4) {
      float4 qe4 = *(const float4*)&qes[i2 * 64 + c4];
      float4 e0 = *(const float4*)(eb + (size_t)(c4 + 0) * 128);
      float4 e1 = *(const float4*)(eb + (size_t)(c4 + 1) * 128);
      float4 e2 = *(const float4*)(eb + (size_t)(c4 + 2) * 128);
      float4 e3 = *(const float4*)(eb + (size_t)(c4 + 3) * 128);
      s0 += qe4.x * e0.x + qe4.y * e1.x + qe4.z * e2.x + qe4.w * e3.x;
      s1 += qe4.x * e0.y + qe4.y * e1.y + qe4.z * e2.y + qe4.w * e3.y;
      s2 += qe4.x * e0.z + qe4.y * e1.z + qe4.z * e2.z + qe4.w * e3.z;
      s3 += qe4.x * e0.w + qe4.y * e1.w + qe4.z * e2.w + qe4.w * e3.w;
    }
    s0 *= 0.125f;
    s1 *= 0.125f;
    s2 *= 0.125f;
    s3 *= 0.125f;
  }
  // P2: softmax within 32-lane group (each group owns one i')
  {
    float mx = fmaxf(fmaxf(s0, s1), fmaxf(s2, s3));
#pragma unroll
    for (int m = 16; m >= 1; m >>= 1) mx = fmaxf(mx, __shfl_xor(mx, m));
    float p0 = expf(s0 - mx), p1 = expf(s1 - mx), p2 = expf(s2 - mx),
          p3 = expf(s3 - mx);
    float sm = p0 + p1 + p2 + p3;
#pragma unroll
    for (int m = 16; m >= 1; m >>= 1) sm += __shfl_xor(sm, m);
    float inv = 1.f / sm;
    float4 a4 = {p0 * inv, p1 * inv, p2 * inv, p3 * inv};
    *(float4*)&att[i2 * 128 + j4 * 4] = a4;
  }
  __syncthreads();

  // P3: av[i'][d], ae[i'][c]. thread = (d = tid&63, half = tid>>6)
  {
    int d = tid & 63, half = tid >> 6;
    float av0 = 0.f, av1 = 0.f, av2 = 0.f, av3 = 0.f;
    float ae0 = 0.f, ae1 = 0.f, ae2 = 0.f, ae3 = 0.f;
    const float* vb = qkv + (size_t)(b * 128) * QKVW + 1024 + h * 64 + d;
    const float* etb = eT + ((size_t)row0 * 128) * 64 + d;
    for (int jq = 0; jq < 16; ++jq) {
      int jb = half * 64 + jq * 4;
      float4 a0 = *(const float4*)&att[0 * 128 + jb];
      float4 a1 = *(const float4*)&att[1 * 128 + jb];
      float4 a2 = *(const float4*)&att[2 * 128 + jb];
      float4 a3 = *(const float4*)&att[3 * 128 + jb];
#pragma unroll
      for (int t = 0; t < 4; ++t) {
        int j = jb + t;
        float vv = vb[(size_t)j * QKVW];
        float at0 = ((const float*)&a0)[t];
        float at1 = ((const float*)&a1)[t];
        float at2 = ((const float*)&a2)[t];
        float at3 = ((const float*)&a3)[t];
        av0 += at0 * vv;
        av1 += at1 * vv;
        av2 += at2 * vv;
        av3 += at3 * vv;
        float e0 = etb[(size_t)j * 64];
        float e1 = etb[8192 + (size_t)j * 64];
        float e2 = etb[16384 + (size_t)j * 64];
        float e3 = etb[24576 + (size_t)j * 64];
        ae0 += at0 * e0;
        ae1 += at1 * e1;
        ae2 += at2 * e2;
        ae3 += at3 * e3;
      }
    }
    avh[half * 256 + 0 * 64 + d] = av0;
    avh[half * 256 + 1 * 64 + d] = av1;
    avh[half * 256 + 2 * 64 + d] = av2;
    avh[half * 256 + 3 * 64 + d] = av3;
    aeh[half * 256 + 0 * 64 + d] = ae0;
    aeh[half * 256 + 1 * 64 + d] = ae1;
    aeh[half * 256 + 2 * 64 + d] = ae2;
    aeh[half * 256 + 3 * 64 + d] = ae3;
  }
  __syncthreads();

  // P4: combine halves, write [av | ae] row segments
  for (int f = tid; f < 256; f += 128) {
    int ii = f >> 6, dd = f & 63;
    attn2[(size_t)(row0 + ii) * 1024 + h * 64 + dd] =
        avh[ii * 64 + dd] + avh[256 + ii * 64 + dd];
    attn2[(size_t)(row0 + ii) * 1024 + 512 + h * 64 + dd] =
        aeh[ii * 64 + dd] + aeh[256 + ii * 64 + dd];
  }
}

// ---------------------------------------------------------------------------
// Gated residual + optional fused LayerNorm of the result.
__global__ __launch_bounds__(256) void gate_ln_kernel(
    const float* __restrict__ x, float* __restrict__ nodes,
    const float* __restrict__ gw, const float* __restrict__ lng,
    const float* __restrict__ lnb, float* __restrict__ xln) {
  __shared__ float red[4];
  int row = blockIdx.x, tid = threadIdx.x;
  float xv = x[(size_t)row * DIMn + tid];
  float rv = nodes[(size_t)row * DIMn + tid];
  float pv =
      xv * gw[tid] + rv * gw[DIMn + tid] + (xv - rv) * gw[2 * DIMn + tid];
  float ssum = block_reduce_sum_256(pv, red);
  float gsig = 1.f / (1.f + expf(-ssum));
  float nv = xv * gsig + rv * (1.f - gsig);
  nodes[(size_t)row * DIMn + tid] = nv;
  if (lng) {
    float m = block_reduce_sum_256(nv, red) * (1.0f / 256.0f);
    float d = nv - m;
    float var = block_reduce_sum_256(d * d, red) * (1.0f / 256.0f);
    float inv = 1.f / sqrtf(var + 1e-5f);
    xln[(size_t)row * DIMn + tid] = d * inv * lng[tid] + lnb[tid];
  }
}

// ---------------------------------------------------------------------------
// VQ nearest neighbor: thread-per-codebook-entry, 4 rows per block.
__global__ __launch_bounds__(256) void vq_kernel(
    const float* __restrict__ nodes, const float* __restrict__ codebook,
    float* __restrict__ out) {
  __shared__ __align__(16) float zs[4 * 256];
  __shared__ float wval[4][4];
  __shared__ int widx[4][4];
  __shared__ int fidx[4];
  int row0 = blockIdx.x * 4;
  int tid = threadIdx.x;
  for (int f = tid; f < 1024; f += 256) zs[f] = nodes[(size_t)row0 * DIMn + f];
  __syncthreads();
  int k1 = tid, k2 = tid + 256;
  const float4* c1p = (const float4*)(codebook + (size_t)k1 * DIMn);
  const float4* c2p = (const float4*)(codebook + (size_t)k2 * DIMn);
  float dot[4][2] = {};
  float cc0 = 0.f, cc1 = 0.f;
#pragma unroll 8
  for (int d4 = 0; d4 < 64; ++d4) {
    float4 c1 = c1p[d4], c2 = c2p[d4];
    cc0 += c1.x * c1.x + c1.y * c1.y + c1.z * c1.z + c1.w * c1.w;
    cc1 += c2.x * c2.x + c2.y * c2.y + c2.z * c2.z + c2.w * c2.w;
#pragma unroll
    for (int r = 0; r < 4; ++r) {
      float4 z = *(const float4*)&zs[r * 256 + d4 * 4];
      dot[r][0] += c1.x * z.x + c1.y * z.y + c1.z * z.z + c1.w * z.w;
      dot[r][1] += c2.x * z.x + c2.y * z.y + c2.z * z.z + c2.w * z.w;
    }
  }
  int lane = tid & 63, w = tid >> 6;
#pragma unroll
  for (int r = 0; r < 4; ++r) {
    float bv = cc0 - 2.f * dot[r][0];
    int bi = k1;
    float v2 = cc1 - 2.f * dot[r][1];
    if (v2 < bv) {
      bv = v2;
      bi = k2;
    }
#pragma unroll
    for (int m = 32; m >= 1; m >>= 1) {
      float ov = __shfl_xor(bv, m);
      int oi = __shfl_xor(bi, m);
      if (ov < bv || (ov == bv && oi < bi)) {
        bv = ov;
        bi = oi;
      }
    }
    if (lane == 0) {
      wval[r][w] = bv;
      widx[r][w] = bi;
    }
  }
  __syncthreads();
  if (tid < 4) {
    float bb = wval[tid][0];
    int bi = widx[tid][0];
    for (int t = 1; t < 4; ++t)
      if (wval[tid][t] < bb || (wval[tid][t] == bb && widx[tid][t] < bi)) {
        bb = wval[tid][t];
        bi = widx[tid][t];
      }
    fidx[tid] = bi;
  }
  __syncthreads();
  for (int f = tid; f < 1024; f += 256) {
    int r = f >> 8, d = f & 255;
    float zv = zs[f];
    float zq = codebook[(size_t)fidx[r] * DIMn + d];
    out[(size_t)(row0 + r) * DIMn + d] = zv + (zq - zv);
  }
}

// ---------------------------------------------------------------------------
extern "C" void kernel_launch(void* const* d_in, const int* in_sizes, int n_in,
                              void* d_out, int out_size, void* d_ws,
                              size_t ws_size, hipStream_t stream) {
  const float* nodes_in = (const float*)d_in[0];
  const float* edges = (const float*)d_in[1];
  const float* edge_ln_g = (const float*)d_in[2];
  const float* edge_ln_b = (const float*)d_in[3];
  const float* ln1_g = (const float*)d_in[4];
  const float* ln1_b = (const float*)d_in[5];
  const float* w_exp = (const float*)d_in[6];
  const float* b_exp = (const float*)d_in[7];
  const float* w_q = (const float*)d_in[8];
  const float* b_q = (const float*)d_in[9];
  const float* w_kv = (const float*)d_in[10];
  const float* b_kv = (const float*)d_in[11];
  const float* w_ekv = (const float*)d_in[12];
  const float* b_ekv = (const float*)d_in[13];
  const float* w_out = (const float*)d_in[14];
  const float* b_out = (const float*)d_in[15];
  const float* gate1_w = (const float*)d_in[16];
  const float* ln2_g = (const float*)d_in[17];
  const float* ln2_b = (const float*)d_in[18];
  const float* w_ff1 = (const float*)d_in[19];
  const float* b_ff1 = (const float*)d_in[20];
  const float* w_ff2 = (const float*)d_in[21];
  const float* b_ff2 = (const float*)d_in[22];
  const float* gate2_w = (const float*)d_in[23];
  const float* codebook = (const float*)d_in[24];

  float* ws = (float*)d_ws;
  float* e_buf = ws;                  // 4194304
  float* eT_buf = e_buf + 4194304;    // 4194304
  float* cost = eT_buf + 4194304;     // 4096
  float* sint = cost + 4096;          // 4096
  float* nodes = sint + 4096;         // 131072
  float* xln = nodes + 131072;        // 131072
  float* xe = xln + 131072;           // 262144
  float* qkvb = xe + 262144;          // 786432
  float* kTb = qkvb + 786432;         // 262144
  float* qeb = kTb + 262144;          // 262144
  float* attn2 = qeb + 262144;        // 524288
  float* proj = attn2 + 524288;       // 131072
  float* ff1 = proj + 131072;         // 524288
  float* W2buf = ff1 + 524288;        // 262144
  float* bout2 = W2buf + 262144;      // 512

  hipMemcpyAsync(nodes, nodes_in, sizeof(float) * Bn * Nn * DIMn,
                 hipMemcpyDeviceToDevice, stream);
  wfold_kernel<<<72, 256, 0, stream>>>(w_ekv, w_out, b_ekv, b_out, W2buf,
                                       bout2);
  edge_ln_kernel<<<512, 128, 0, stream>>>(edges, edge_ln_g, edge_ln_b, e_buf,
                                          eT_buf);
  rope_table_kernel<<<16, 256, 0, stream>>>(cost, sint);

  for (int l = 0; l < DEPTHn; ++l) {
    if (l == 0)
      ln_kernel<<<512, 256, 0, stream>>>(nodes, ln1_g, ln1_b, xln);
    gemm_kernel<<<dim3(8, 16), 256, 0, stream>>>(
        xln, w_exp + l * 256 * 512, 512, b_exp + l * 512, nullptr, 0, nullptr,
        nullptr, 0, xe, 512, 512, 256, 0, cost, sint, nullptr);
    gemm_kernel<<<dim3(24, 16), 256, 0, stream>>>(
        xe, w_q + l * 512 * 512, 512, b_q + l * 512, w_kv + l * 512 * 1024,
        1024, b_kv + l * 1024, nullptr, 0, qkvb, 512, QKVW, 512, 4, cost, sint,
        kTb);
    qe_kernel<<<128, 256, 0, stream>>>(qkvb, w_ekv + l * 64 * 512, qeb);
    attn_kernel<<<1024, 128, 0, stream>>>(qkvb, e_buf, eT_buf, kTb, qeb,
                                          attn2);
    gemm_kernel<<<dim3(4, 16), 256, 0, stream>>>(
        attn2, w_out + l * 512 * 256, 256, bout2 + l * 256, nullptr, 0,
        nullptr, W2buf + l * 512 * 256, 512, proj, 512, 256, 1024, 0, cost,
        sint, nullptr);
    gate_ln_kernel<<<512, 256, 0, stream>>>(proj, nodes, gate1_w + l * 768,
                                            ln2_g + l * 256, ln2_b + l * 256,
                                            xln);
    gemm_kernel<<<dim3(16, 16), 256, 0, stream>>>(
        xln, w_ff1 + l * 256 * 1024, 1024, b_ff1 + l * 1024, nullptr, 0,
        nullptr, nullptr, 0, ff1, 512, 1024, 256, 1, cost, sint, nullptr);
    gemm_kernel<<<dim3(4, 16), 256, 0, stream>>>(
        ff1, w_ff2 + l * 1024 * 256, 256, b_ff2 + l * 256, nullptr, 0, nullptr,
        nullptr, 0, proj, 512, 256, 1024, 0, cost, sint, nullptr);
    const float* nlng = (l + 1 < DEPTHn) ? ln1_g + (l + 1) * 256 : nullptr;
    const float* nlnb = (l + 1 < DEPTHn) ? ln1_b + (l + 1) * 256 : nullptr;
    gate_ln_kernel<<<512, 256, 0, stream>>>(proj, nodes, gate2_w + l * 768,
                                            nlng, nlnb, xln);
  }
  vq_kernel<<<128, 256, 0, stream>>>(nodes, codebook, (float*)d_out);
}

// Round 5
// 381.113 us; speedup vs baseline: 1.4225x; 1.2377x over previous
//
#include <hip/hip_runtime.h>
#include <math.h>

// VQVAE graph-transformer forward, fp32 throughout.
// B=4 N=128 DIM=256 HEADS=8 DH=64 EDGE=64 DEPTH=2 K=512 INNER=512
// ekv = e@w_ekv never materialized. R5:
//  - split-K GEMMs (out-proj, ff2: z=4; exp: z=2) -> >=256 blocks/dispatch;
//    partial sums fused into consumers (gate_ln sums 4; qkv-GEMM A-stage sums 2)
//  - register double-buffered K-loop in all GEMMs (prefetch overlap compute)

#define DEV __device__ __forceinline__

constexpr int Bn = 4, Nn = 128, DIMn = 256, HEADSn = 8, DHn = 64, EDGEn = 64,
              DEPTHn = 2, Kn = 512, INNERn = 512;
constexpr int QKVW = 1536;

DEV float wave_reduce_sum(float v) {
#pragma unroll
  for (int m = 32; m >= 1; m >>= 1) v += __shfl_xor(v, m);
  return v;
}

DEV float block_reduce_sum_256(float v, float* red) {
  v = wave_reduce_sum(v);
  int tid = threadIdx.x;
  if ((tid & 63) == 0) red[tid >> 6] = v;
  __syncthreads();
  v = red[0] + red[1] + red[2] + red[3];
  __syncthreads();
  return v;
}

// ---------------------------------------------------------------------------
// Edge LayerNorm -> e[b][i][c][j]  AND  eT[b][i][j][c]. Block per (b,i).
__global__ __launch_bounds__(128) void edge_ln_kernel(
    const float* __restrict__ edges, const float* __restrict__ g,
    const float* __restrict__ bta, float* __restrict__ e,
    float* __restrict__ eT) {
  __shared__ float ets[128 * 65];
  int blk = blockIdx.x;  // b*128 + i
  int i = blk & 127, b = blk >> 7;
  int j = threadIdx.x;
  const float* src = edges + (size_t)b * EDGEn * Nn * Nn + i * Nn + j;
  float vals[EDGEn];
  float s = 0.f;
#pragma unroll
  for (int c = 0; c < EDGEn; ++c) {
    float x = src[(size_t)c * (Nn * Nn)];
    vals[c] = x;
    s += x;
  }
  float m = s * (1.0f / 64.0f);
  float s2 = 0.f;
#pragma unroll
  for (int c = 0; c < EDGEn; ++c) {
    float d = vals[c] - m;
    s2 += d * d;
  }
  float inv = 1.f / sqrtf(s2 * (1.0f / 64.0f) + 1e-5f);
  float* dst = e + ((size_t)(b * Nn + i) * EDGEn) * Nn + j;
#pragma unroll
  for (int c = 0; c < EDGEn; ++c) {
    float o = (vals[c] - m) * inv * g[c] + bta[c];
    dst[(size_t)c * Nn] = o;
    ets[j * 65 + c] = o;
  }
  __syncthreads();
  float* dstT = eT + ((size_t)(b * Nn + i) * Nn) * EDGEn;
#pragma unroll
  for (int it = 0; it < 16; ++it) {
    int f4 = it * 128 + j;
    int jj = f4 >> 4, c4 = (f4 & 15) << 2;
    float4 o4 = {ets[jj * 65 + c4], ets[jj * 65 + c4 + 1],
                 ets[jj * 65 + c4 + 2], ets[jj * 65 + c4 + 3]};
    *(float4*)(dstT + (size_t)jj * EDGEn + c4) = o4;
  }
}

// ---------------------------------------------------------------------------
__global__ void rope_table_kernel(float* __restrict__ cost,
                                  float* __restrict__ sint) {
  int t = blockIdx.x * 256 + threadIdx.x;
  if (t >= Nn * 32) return;
  int n = t >> 5, p = t & 31;
  float inv = powf(10000.f, -(float)(2 * p) / 64.f);
  float fr = (float)n * inv;
  cost[t] = cosf(fr);
  sint[t] = sinf(fr);
}

// ---------------------------------------------------------------------------
// Fold kernel: W2[l][h*64+c][n] = sum_d wek[l][c][h64+d] * w_out[l][h64+d][n]
// and b_out2[l][n] = b_out[l][n] + sum_k bek[l][k]*w_out[l][k][n].
__global__ __launch_bounds__(256) void wfold_kernel(
    const float* __restrict__ wek, const float* __restrict__ w_out,
    const float* __restrict__ bek, const float* __restrict__ b_out,
    float* __restrict__ W2, float* __restrict__ b_out2) {
  int blk = blockIdx.x;
  int tid = threadIdx.x;
  if (blk < 64) {
    int l = blk >> 5, h = (blk >> 2) & 7, nt = blk & 3;
    __shared__ float As[64 * 65];  // [c][d]
    __shared__ float Bs[64 * 68];  // [d][n]
    const float* wekl = wek + (size_t)l * 64 * 512 + h * 64;
    const float* woutl =
        w_out + (size_t)l * 512 * 256 + (size_t)(h * 64) * 256 + nt * 64;
    for (int f = tid; f < 1024; f += 256) {
      int c = f >> 4, d4 = (f & 15) << 2;
      float4 w4 = *(const float4*)(wekl + (size_t)c * 512 + d4);
      As[c * 65 + d4 + 0] = w4.x;
      As[c * 65 + d4 + 1] = w4.y;
      As[c * 65 + d4 + 2] = w4.z;
      As[c * 65 + d4 + 3] = w4.w;
    }
    for (int f = tid; f < 1024; f += 256) {
      int d = f >> 4, n4 = (f & 15) << 2;
      float4 w4 = *(const float4*)(woutl + (size_t)d * 256 + n4);
      Bs[d * 68 + n4 + 0] = w4.x;
      Bs[d * 68 + n4 + 1] = w4.y;
      Bs[d * 68 + n4 + 2] = w4.z;
      Bs[d * 68 + n4 + 3] = w4.w;
    }
    __syncthreads();
    int tx = tid & 15, ty = tid >> 4;
    float acc[4][4] = {};
    for (int d = 0; d < 64; ++d) {
      float4 bv = *(const float4*)&Bs[d * 68 + tx * 4];
#pragma unroll
      for (int u = 0; u < 4; ++u) {
        float a = As[(ty * 4 + u) * 65 + d];
        acc[u][0] += a * bv.x;
        acc[u][1] += a * bv.y;
        acc[u][2] += a * bv.z;
        acc[u][3] += a * bv.w;
      }
    }
#pragma unroll
    for (int u = 0; u < 4; ++u) {
      float4 o = {acc[u][0], acc[u][1], acc[u][2], acc[u][3]};
      *(float4*)(W2 + (size_t)l * 512 * 256 +
                 (size_t)(h * 64 + ty * 4 + u) * 256 + nt * 64 + tx * 4) = o;
    }
  } else {
    int t = blk - 64;
    int l = t >> 2, nt = t & 3;
    __shared__ float part[256];
    int nn = tid & 63, kq = tid >> 6;
    const float* wcol = w_out + (size_t)l * 512 * 256 + nt * 64 + nn;
    float acc = 0.f;
    for (int k = kq * 128; k < kq * 128 + 128; ++k)
      acc += bek[l * 512 + k] * wcol[(size_t)k * 256];
    part[tid] = acc;
    __syncthreads();
    if (tid < 64)
      b_out2[l * 256 + nt * 64 + nn] =
          b_out[l * 256 + nt * 64 + nn] + part[nn] + part[64 + nn] +
          part[128 + nn] + part[192 + nn];
  }
}

// ---------------------------------------------------------------------------
// Row LayerNorm over DIM=256 (layer-0 entry only).
__global__ __launch_bounds__(256) void ln_kernel(const float* __restrict__ x,
                                                 const float* __restrict__ g,
                                                 const float* __restrict__ b,
                                                 float* __restrict__ y) {
  __shared__ float red[4];
  int row = blockIdx.x, tid = threadIdx.x;
  float v = x[(size_t)row * DIMn + tid];
  float m = block_reduce_sum_256(v, red) * (1.0f / 256.0f);
  float d = v - m;
  float var = block_reduce_sum_256(d * d, red) * (1.0f / 256.0f);
  float inv = 1.f / sqrtf(var + 1e-5f);
  y[(size_t)row * DIMn + tid] = d * inv * g[tid] + b[tid];
}

// ---------------------------------------------------------------------------
// fp32 GEMM, 32x64 tile, BK=32, 2x4 microtile, register double-buffered.
// Dual-N (W2n at col>=N1), dual-K (global k>=Ksplit reads Wkb),
// split-K (blockIdx.z covers kspan rows; C offset z*M*Ntot; bias only z==0),
// optional A2 (A-stage sums two partial buffers).
// act: 0 none, 1 exact gelu, 4 qkv mode (rope cols<1024; k section -> kT).
__global__ __launch_bounds__(256) void gemm_kernel(
    const float* __restrict__ A, const float* __restrict__ A2,
    const float* __restrict__ W1, int N1, const float* __restrict__ b1,
    const float* __restrict__ W2n, int N2, const float* __restrict__ b2,
    const float* __restrict__ Wkb, int Ksplit, float* __restrict__ C, int M,
    int Ntot, int K, int kspan, int act, const float* __restrict__ cost,
    const float* __restrict__ sint, float* __restrict__ kT) {
  __shared__ float As[32][34];
  __shared__ __align__(16) float Bs[32][68];
  int tid = threadIdx.x;
  int bx = blockIdx.x, by = blockIdx.y, zid = blockIdx.z;
  int tx = tid & 15, ty = tid >> 4;
  int arow = tid >> 3, acol = (tid & 7) << 2;
  int brow = tid >> 4, bcol = (tid & 15) << 2;
  int col0 = bx * 64;
  const float* W = W1;
  const float* bias = b1;
  int Nw = N1, wcol = col0;
  if (W2n && col0 >= N1) {
    W = W2n;
    bias = b2;
    Nw = N2;
    wcol = col0 - N1;
  }
  int kb = zid * kspan, kend = kb + kspan;
  const float* arp = A + (size_t)(by * 32 + arow) * K;
  const float* arp2 = A2 ? A2 + (size_t)(by * 32 + arow) * K : nullptr;

  // prefetch slab kb
  float4 a_nxt = *(const float4*)(arp + kb + acol);
  if (arp2) {
    float4 a2 = *(const float4*)(arp2 + kb + acol);
    a_nxt.x += a2.x;
    a_nxt.y += a2.y;
    a_nxt.z += a2.z;
    a_nxt.w += a2.w;
  }
  const float* w0p;
  const float* w1p;
  {
    int kr0 = kb + brow, kr1 = kb + brow + 16;
    w0p = (Ksplit && kr0 >= Ksplit)
              ? Wkb + (size_t)(kr0 - Ksplit) * Nw + wcol + bcol
              : W + (size_t)kr0 * Nw + wcol + bcol;
    w1p = (Ksplit && kr1 >= Ksplit)
              ? Wkb + (size_t)(kr1 - Ksplit) * Nw + wcol + bcol
              : W + (size_t)kr1 * Nw + wcol + bcol;
  }
  float4 b0_nxt = *(const float4*)w0p;
  float4 b1_nxt = *(const float4*)w1p;

  float acc[2][4] = {};
  for (int k0 = kb; k0 < kend; k0 += 32) {
    As[acol + 0][arow] = a_nxt.x;
    As[acol + 1][arow] = a_nxt.y;
    As[acol + 2][arow] = a_nxt.z;
    As[acol + 3][arow] = a_nxt.w;
    *(float4*)&Bs[brow][bcol] = b0_nxt;
    *(float4*)&Bs[brow + 16][bcol] = b1_nxt;
    __syncthreads();
    int kn = k0 + 32;
    if (kn < kend) {
      a_nxt = *(const float4*)(arp + kn + acol);
      if (arp2) {
        float4 a2 = *(const float4*)(arp2 + kn + acol);
        a_nxt.x += a2.x;
        a_nxt.y += a2.y;
        a_nxt.z += a2.z;
        a_nxt.w += a2.w;
      }
      int kr0 = kn + brow, kr1 = kn + brow + 16;
      w0p = (Ksplit && kr0 >= Ksplit)
                ? Wkb + (size_t)(kr0 - Ksplit) * Nw + wcol + bcol
                : W + (size_t)kr0 * Nw + wcol + bcol;
      w1p = (Ksplit && kr1 >= Ksplit)
                ? Wkb + (size_t)(kr1 - Ksplit) * Nw + wcol + bcol
                : W + (size_t)kr1 * Nw + wcol + bcol;
      b0_nxt = *(const float4*)w0p;
      b1_nxt = *(const float4*)w1p;
    }
#pragma unroll
    for (int kk = 0; kk < 32; ++kk) {
      float2 av = *(const float2*)&As[kk][ty * 2];
      float4 bv = *(const float4*)&Bs[kk][tx * 4];
      acc[0][0] += av.x * bv.x;
      acc[0][1] += av.x * bv.y;
      acc[0][2] += av.x * bv.z;
      acc[0][3] += av.x * bv.w;
      acc[1][0] += av.y * bv.x;
      acc[1][1] += av.y * bv.y;
      acc[1][2] += av.y * bv.z;
      acc[1][3] += av.y * bv.w;
    }
    __syncthreads();
  }
  int ccol = wcol + tx * 4;
  bool ksec = (act == 4) && (col0 >= 512) && (col0 < 1024);
  float* trans = (float*)Bs;
  float* Cz = C + (size_t)zid * M * Ntot;
#pragma unroll
  for (int u = 0; u < 2; ++u) {
    int r = by * 32 + ty * 2 + u;
    float o[4];
#pragma unroll
    for (int w = 0; w < 4; ++w)
      o[w] = acc[u][w] + (zid == 0 ? bias[ccol + w] : 0.f);
    if (act == 1) {
#pragma unroll
      for (int w = 0; w < 4; ++w)
        o[w] = 0.5f * o[w] * (1.f + erff(o[w] * 0.70710678118654752f));
    } else if (act == 4 && col0 < 1024) {
      int n = r & 127;
      int p0 = (ccol & 63) >> 1;
      float c0 = cost[n * 32 + p0], s0 = sint[n * 32 + p0];
      float c1 = cost[n * 32 + p0 + 1], s1 = sint[n * 32 + p0 + 1];
      float x0 = o[0], x1 = o[1], x2 = o[2], x3 = o[3];
      o[0] = x0 * c0 - x1 * s0;
      o[1] = x1 * c0 + x0 * s0;
      o[2] = x2 * c1 - x3 * s1;
      o[3] = x3 * c1 + x2 * s1;
    }
    if (ksec) {
      int jl = ty * 2 + u;
#pragma unroll
      for (int w = 0; w < 4; ++w) trans[(tx * 4 + w) * 33 + jl] = o[w];
    } else {
      float4 o4 = {o[0], o[1], o[2], o[3]};
      *(float4*)(Cz + (size_t)r * Ntot + col0 + tx * 4) = o4;
    }
  }
  if (ksec) {
    __syncthreads();
    int h = (col0 - 512) >> 6;
    int bb = (by * 32) >> 7;
#pragma unroll
    for (int q = 0; q < 2; ++q) {
      int f4 = tid * 2 + q;
      int dl = f4 >> 3, j4 = (f4 & 7) << 2;
      int jj = (by * 32 + j4) & 127;
      float4 o4 = {trans[dl * 33 + j4], trans[dl * 33 + j4 + 1],
                   trans[dl * 33 + j4 + 2], trans[dl * 33 + j4 + 3]};
      *(float4*)(kT + ((size_t)(bb * 8 + h) * 64 + dl) * 128 + jj) = o4;
    }
  }
}

// ---------------------------------------------------------------------------
// qe[b,h,i,c] = sum_d q_rot[b,i,h64+d] * wek[c,h64+d]. Block=(b,h,iq of 32 i).
__global__ __launch_bounds__(256) void qe_kernel(const float* __restrict__ qkv,
                                                 const float* __restrict__ wek,
                                                 float* __restrict__ qe) {
  __shared__ float qs[32 * 65];
  __shared__ float ws[64 * 65];
  int blk = blockIdx.x;
  int iq = blk & 3;
  int bh = blk >> 2;
  int b = bh >> 3, h = bh & 7;
  int i0 = iq * 32;
  int tid = threadIdx.x;
  for (int f = tid; f < 32 * 64; f += 256) {
    int i = f >> 6, d = f & 63;
    qs[i * 65 + d] = qkv[(size_t)(b * 128 + i0 + i) * QKVW + h * 64 + d];
  }
  for (int f = tid; f < 64 * 64; f += 256) {
    int c = f >> 6, d = f & 63;
    ws[c * 65 + d] = wek[(size_t)c * INNERn + h * 64 + d];
  }
  __syncthreads();
  int c = tid & 63, i2 = tid >> 6;
  for (int ib = 0; ib < 8; ++ib) {
    int i = ib * 4 + i2;
    float acc = 0.f;
#pragma unroll
    for (int d = 0; d < 64; ++d) acc += qs[i * 65 + d] * ws[c * 65 + d];
    qe[((size_t)bh * 128 + i0 + i) * 64 + c] = acc;
  }
}

// ---------------------------------------------------------------------------
// Attention core: block per (b,h,i-quad), 128 threads. Writes [av|ae] rows.
__global__ __launch_bounds__(128) void attn_kernel(
    const float* __restrict__ qkv, const float* __restrict__ e,
    const float* __restrict__ eT, const float* __restrict__ kT,
    const float* __restrict__ qeb, float* __restrict__ attn2) {
  __shared__ __align__(16) float qs[256];
  __shared__ __align__(16) float qes[256];
  __shared__ __align__(16) float att[512];
  __shared__ float avh[512];
  __shared__ float aeh[512];
  int blk = blockIdx.x;
  int iq = blk & 31;
  int bh = blk >> 5;
  int h = bh & 7, b = bh >> 3;
  int i0 = iq * 4;
  int row0 = b * 128 + i0;
  int tid = threadIdx.x;

  for (int f = tid; f < 256; f += 128) {
    int ii = f >> 6, d = f & 63;
    qs[f] = qkv[(size_t)(row0 + ii) * QKVW + h * 64 + d];
    qes[f] = qeb[((size_t)bh * 128 + i0 + ii) * 64 + d];
  }
  __syncthreads();

  int i2 = tid >> 5, j4 = tid & 31;
  float s0 = 0.f, s1 = 0.f, s2 = 0.f, s3 = 0.f;
  {
    const float* ktb = kT + ((size_t)bh * 64) * 128 + j4 * 4;
#pragma unroll
    for (int d4 = 0; d4 < 64; d4 += 4) {
      float4 q4 = *(const float4*)&qs[i2 * 64 + d4];
      float4 k0 = *(const float4*)(ktb + (size_t)(d4 + 0) * 128);
      float4 k1 = *(const float4*)(ktb + (size_t)(d4 + 1) * 128);
      float4 k2 = *(const float4*)(ktb + (size_t)(d4 + 2) * 128);
      float4 k3 = *(const float4*)(ktb + (size_t)(d4 + 3) * 128);
      s0 += q4.x * k0.x + q4.y * k1.x + q4.z * k2.x + q4.w * k3.x;
      s1 += q4.x * k0.y + q4.y * k1.y + q4.z * k2.y + q4.w * k3.y;
      s2 += q4.x * k0.z + q4.y * k1.z + q4.z * k2.z + q4.w * k3.z;
      s3 += q4.x * k0.w + q4.y * k1.w + q4.z * k2.w + q4.w * k3.w;
    }
    const float* eb = e + ((size_t)(row0 + i2) * 64) * 128 + j4 * 4;
#pragma unroll
    for (int c4 = 0; c4 < 64; c4 += 4) {
      float4 qe4 = *(const float4*)&qes[i2 * 64 + c4];
      float4 e0 = *(const float4*)(eb + (size_t)(c4 + 0) * 128);
      float4 e1 = *(const float4*)(eb + (size_t)(c4 + 1) * 128);
      float4 e2 = *(const float4*)(eb + (size_t)(c4 + 2) * 128);
      float4 e3 = *(const float4*)(eb + (size_t)(c4 + 3) * 128);
      s0 += qe4.x * e0.x + qe4.y * e1.x + qe4.z * e2.x + qe4.w * e3.x;
      s1 += qe4.x * e0.y + qe4.y * e1.y + qe4.z * e2.y + qe4.w * e3.y;
      s2 += qe4.x * e0.z + qe4.y * e1.z + qe4.z * e2.z + qe4.w * e3.z;
      s3 += qe4.x * e0.w + qe4.y * e1.w + qe4.z * e2.w + qe4.w * e3.w;
    }
    s0 *= 0.125f;
    s1 *= 0.125f;
    s2 *= 0.125f;
    s3 *= 0.125f;
  }
  {
    float mx = fmaxf(fmaxf(s0, s1), fmaxf(s2, s3));
#pragma unroll
    for (int m = 16; m >= 1; m >>= 1) mx = fmaxf(mx, __shfl_xor(mx, m));
    float p0 = expf(s0 - mx), p1 = expf(s1 - mx), p2 = expf(s2 - mx),
          p3 = expf(s3 - mx);
    float sm = p0 + p1 + p2 + p3;
#pragma unroll
    for (int m = 16; m >= 1; m >>= 1) sm += __shfl_xor(sm, m);
    float inv = 1.f / sm;
    float4 a4 = {p0 * inv, p1 * inv, p2 * inv, p3 * inv};
    *(float4*)&att[i2 * 128 + j4 * 4] = a4;
  }
  __syncthreads();

  {
    int d = tid & 63, half = tid >> 6;
    float av0 = 0.f, av1 = 0.f, av2 = 0.f, av3 = 0.f;
    float ae0 = 0.f, ae1 = 0.f, ae2 = 0.f, ae3 = 0.f;
    const float* vb = qkv + (size_t)(b * 128) * QKVW + 1024 + h * 64 + d;
    const float* etb = eT + ((size_t)row0 * 128) * 64 + d;
    for (int jq = 0; jq < 16; ++jq) {
      int jb = half * 64 + jq * 4;
      float4 a0 = *(const float4*)&att[0 * 128 + jb];
      float4 a1 = *(const float4*)&att[1 * 128 + jb];
      float4 a2 = *(const float4*)&att[2 * 128 + jb];
      float4 a3 = *(const float4*)&att[3 * 128 + jb];
#pragma unroll
      for (int t = 0; t < 4; ++t) {
        int j = jb + t;
        float vv = vb[(size_t)j * QKVW];
        float at0 = ((const float*)&a0)[t];
        float at1 = ((const float*)&a1)[t];
        float at2 = ((const float*)&a2)[t];
        float at3 = ((const float*)&a3)[t];
        av0 += at0 * vv;
        av1 += at1 * vv;
        av2 += at2 * vv;
        av3 += at3 * vv;
        float e0 = etb[(size_t)j * 64];
        float e1 = etb[8192 + (size_t)j * 64];
        float e2 = etb[16384 + (size_t)j * 64];
        float e3 = etb[24576 + (size_t)j * 64];
        ae0 += at0 * e0;
        ae1 += at1 * e1;
        ae2 += at2 * e2;
        ae3 += at3 * e3;
      }
    }
    avh[half * 256 + 0 * 64 + d] = av0;
    avh[half * 256 + 1 * 64 + d] = av1;
    avh[half * 256 + 2 * 64 + d] = av2;
    avh[half * 256 + 3 * 64 + d] = av3;
    aeh[half * 256 + 0 * 64 + d] = ae0;
    aeh[half * 256 + 1 * 64 + d] = ae1;
    aeh[half * 256 + 2 * 64 + d] = ae2;
    aeh[half * 256 + 3 * 64 + d] = ae3;
  }
  __syncthreads();

  for (int f = tid; f < 256; f += 128) {
    int ii = f >> 6, dd = f & 63;
    attn2[(size_t)(row0 + ii) * 1024 + h * 64 + dd] =
        avh[ii * 64 + dd] + avh[256 + ii * 64 + dd];
    attn2[(size_t)(row0 + ii) * 1024 + 512 + h * 64 + dd] =
        aeh[ii * 64 + dd] + aeh[256 + ii * 64 + dd];
  }
}

// ---------------------------------------------------------------------------
// Gated residual + optional fused LayerNorm. x = sum of nparts partial buffers
// (stride 131072 floats).
__global__ __launch_bounds__(256) void gate_ln_kernel(
    const float* __restrict__ x, int nparts, float* __restrict__ nodes,
    const float* __restrict__ gw, const float* __restrict__ lng,
    const float* __restrict__ lnb, float* __restrict__ xln) {
  __shared__ float red[4];
  int row = blockIdx.x, tid = threadIdx.x;
  size_t off = (size_t)row * DIMn + tid;
  float xv = x[off];
  if (nparts == 4)
    xv += x[off + 131072] + x[off + 262144] + x[off + 393216];
  float rv = nodes[off];
  float pv =
      xv * gw[tid] + rv * gw[DIMn + tid] + (xv - rv) * gw[2 * DIMn + tid];
  float ssum = block_reduce_sum_256(pv, red);
  float gsig = 1.f / (1.f + expf(-ssum));
  float nv = xv * gsig + rv * (1.f - gsig);
  nodes[off] = nv;
  if (lng) {
    float m = block_reduce_sum_256(nv, red) * (1.0f / 256.0f);
    float d = nv - m;
    float var = block_reduce_sum_256(d * d, red) * (1.0f / 256.0f);
    float inv = 1.f / sqrtf(var + 1e-5f);
    xln[off] = d * inv * lng[tid] + lnb[tid];
  }
}

// ---------------------------------------------------------------------------
// VQ nearest neighbor: thread-per-codebook-entry, 4 rows per block.
__global__ __launch_bounds__(256) void vq_kernel(
    const float* __restrict__ nodes, const float* __restrict__ codebook,
    float* __restrict__ out) {
  __shared__ __align__(16) float zs[4 * 256];
  __shared__ float wval[4][4];
  __shared__ int widx[4][4];
  __shared__ int fidx[4];
  int row0 = blockIdx.x * 4;
  int tid = threadIdx.x;
  for (int f = tid; f < 1024; f += 256) zs[f] = nodes[(size_t)row0 * DIMn + f];
  __syncthreads();
  int k1 = tid, k2 = tid + 256;
  const float4* c1p = (const float4*)(codebook + (size_t)k1 * DIMn);
  const float4* c2p = (const float4*)(codebook + (size_t)k2 * DIMn);
  float dot[4][2] = {};
  float cc0 = 0.f, cc1 = 0.f;
#pragma unroll 8
  for (int d4 = 0; d4 < 64; ++d4) {
    float4 c1 = c1p[d4], c2 = c2p[d4];
    cc0 += c1.x * c1.x + c1.y * c1.y + c1.z * c1.z + c1.w * c1.w;
    cc1 += c2.x * c2.x + c2.y * c2.y + c2.z * c2.z + c2.w * c2.w;
#pragma unroll
    for (int r = 0; r < 4; ++r) {
      float4 z = *(const float4*)&zs[r * 256 + d4 * 4];
      dot[r][0] += c1.x * z.x + c1.y * z.y + c1.z * z.z + c1.w * z.w;
      dot[r][1] += c2.x * z.x + c2.y * z.y + c2.z * z.z + c2.w * z.w;
    }
  }
  int lane = tid & 63, w = tid >> 6;
#pragma unroll
  for (int r = 0; r < 4; ++r) {
    float bv = cc0 - 2.f * dot[r][0];
    int bi = k1;
    float v2 = cc1 - 2.f * dot[r][1];
    if (v2 < bv) {
      bv = v2;
      bi = k2;
    }
#pragma unroll
    for (int m = 32; m >= 1; m >>= 1) {
      float ov = __shfl_xor(bv, m);
      int oi = __shfl_xor(bi, m);
      if (ov < bv || (ov == bv && oi < bi)) {
        bv = ov;
        bi = oi;
      }
    }
    if (lane == 0) {
      wval[r][w] = bv;
      widx[r][w] = bi;
    }
  }
  __syncthreads();
  if (tid < 4) {
    float bb = wval[tid][0];
    int bi = widx[tid][0];
    for (int t = 1; t < 4; ++t)
      if (wval[tid][t] < bb || (wval[tid][t] == bb && widx[tid][t] < bi)) {
        bb = wval[tid][t];
        bi = widx[tid][t];
      }
    fidx[tid] = bi;
  }
  __syncthreads();
  for (int f = tid; f < 1024; f += 256) {
    int r = f >> 8, d = f & 255;
    float zv = zs[f];
    float zq = codebook[(size_t)fidx[r] * DIMn + d];
    out[(size_t)(row0 + r) * DIMn + d] = zv + (zq - zv);
  }
}

// ---------------------------------------------------------------------------
extern "C" void kernel_launch(void* const* d_in, const int* in_sizes, int n_in,
                              void* d_out, int out_size, void* d_ws,
                              size_t ws_size, hipStream_t stream) {
  const float* nodes_in = (const float*)d_in[0];
  const float* edges = (const float*)d_in[1];
  const float* edge_ln_g = (const float*)d_in[2];
  const float* edge_ln_b = (const float*)d_in[3];
  const float* ln1_g = (const float*)d_in[4];
  const float* ln1_b = (const float*)d_in[5];
  const float* w_exp = (const float*)d_in[6];
  const float* b_exp = (const float*)d_in[7];
  const float* w_q = (const float*)d_in[8];
  const float* b_q = (const float*)d_in[9];
  const float* w_kv = (const float*)d_in[10];
  const float* b_kv = (const float*)d_in[11];
  const float* w_ekv = (const float*)d_in[12];
  const float* b_ekv = (const float*)d_in[13];
  const float* w_out = (const float*)d_in[14];
  const float* b_out = (const float*)d_in[15];
  const float* gate1_w = (const float*)d_in[16];
  const float* ln2_g = (const float*)d_in[17];
  const float* ln2_b = (const float*)d_in[18];
  const float* w_ff1 = (const float*)d_in[19];
  const float* b_ff1 = (const float*)d_in[20];
  const float* w_ff2 = (const float*)d_in[21];
  const float* b_ff2 = (const float*)d_in[22];
  const float* gate2_w = (const float*)d_in[23];
  const float* codebook = (const float*)d_in[24];

  float* ws = (float*)d_ws;
  float* e_buf = ws;                  // 4194304
  float* eT_buf = e_buf + 4194304;    // 4194304
  float* cost = eT_buf + 4194304;     // 4096
  float* sint = cost + 4096;          // 4096
  float* nodes = sint + 4096;         // 131072
  float* xln = nodes + 131072;        // 131072
  float* xe = xln + 131072;           // 524288 (2 split-K partials)
  float* qkvb = xe + 524288;          // 786432
  float* kTb = qkvb + 786432;         // 262144
  float* qeb = kTb + 262144;          // 262144
  float* attn2 = qeb + 262144;        // 524288
  float* proj = attn2 + 524288;       // 524288 (4 split-K partials)
  float* ff1 = proj + 524288;         // 524288
  float* W2buf = ff1 + 524288;        // 262144
  float* bout2 = W2buf + 262144;      // 512

  hipMemcpyAsync(nodes, nodes_in, sizeof(float) * Bn * Nn * DIMn,
                 hipMemcpyDeviceToDevice, stream);
  wfold_kernel<<<72, 256, 0, stream>>>(w_ekv, w_out, b_ekv, b_out, W2buf,
                                       bout2);
  edge_ln_kernel<<<512, 128, 0, stream>>>(edges, edge_ln_g, edge_ln_b, e_buf,
                                          eT_buf);
  rope_table_kernel<<<16, 256, 0, stream>>>(cost, sint);

  for (int l = 0; l < DEPTHn; ++l) {
    if (l == 0)
      ln_kernel<<<512, 256, 0, stream>>>(nodes, ln1_g, ln1_b, xln);
    // exp: split-K x2 -> xe partials (each 512x512)
    gemm_kernel<<<dim3(8, 16, 2), 256, 0, stream>>>(
        xln, nullptr, w_exp + l * 256 * 512, 512, b_exp + l * 512, nullptr, 0,
        nullptr, nullptr, 0, xe, 512, 512, 256, 128, 0, cost, sint, nullptr);
    // fused q|kv (A = sum of 2 xe partials), rope epilogue + kT scatter
    gemm_kernel<<<dim3(24, 16, 1), 256, 0, stream>>>(
        xe, xe + 262144, w_q + l * 512 * 512, 512, b_q + l * 512,
        w_kv + l * 512 * 1024, 1024, b_kv + l * 1024, nullptr, 0, qkvb, 512,
        QKVW, 512, 512, 4, cost, sint, kTb);
    qe_kernel<<<128, 256, 0, stream>>>(qkvb, w_ekv + l * 64 * 512, qeb);
    attn_kernel<<<1024, 128, 0, stream>>>(qkvb, e_buf, eT_buf, kTb, qeb,
                                          attn2);
    // out-proj: dual-K (w_out | W2buf) + split-K x4 -> proj partials
    gemm_kernel<<<dim3(4, 16, 4), 256, 0, stream>>>(
        attn2, nullptr, w_out + l * 512 * 256, 256, bout2 + l * 256, nullptr,
        0, nullptr, W2buf + l * 512 * 256, 512, proj, 512, 256, 1024, 256, 0,
        cost, sint, nullptr);
    gate_ln_kernel<<<512, 256, 0, stream>>>(proj, 4, nodes, gate1_w + l * 768,
                                            ln2_g + l * 256, ln2_b + l * 256,
                                            xln);
    gemm_kernel<<<dim3(16, 16, 1), 256, 0, stream>>>(
        xln, nullptr, w_ff1 + l * 256 * 1024, 1024, b_ff1 + l * 1024, nullptr,
        0, nullptr, nullptr, 0, ff1, 512, 1024, 256, 256, 1, cost, sint,
        nullptr);
    // ff2: split-K x4 -> proj partials
    gemm_kernel<<<dim3(4, 16, 4), 256, 0, stream>>>(
        ff1, nullptr, w_ff2 + l * 1024 * 256, 256, b_ff2 + l * 256, nullptr, 0,
        nullptr, nullptr, 0, proj, 512, 256, 1024, 256, 0, cost, sint,
        nullptr);
    const float* nlng = (l + 1 < DEPTHn) ? ln1_g + (l + 1) * 256 : nullptr;
    const float* nlnb = (l + 1 < DEPTHn) ? ln1_b + (l + 1) * 256 : nullptr;
    gate_ln_kernel<<<512, 256, 0, stream>>>(proj, 4, nodes, gate2_w + l * 768,
                                            nlng, nlnb, xln);
  }
  vq_kernel<<<128, 256, 0, stream>>>(nodes, codebook, (float*)d_out);
}

// Round 6
// 367.038 us; speedup vs baseline: 1.4771x; 1.0383x over previous
//
#include <hip/hip_runtime.h>
#include <math.h>

// VQVAE graph-transformer forward, fp32 throughout.
// B=4 N=128 DIM=256 HEADS=8 DH=64 EDGE=64 DEPTH=2 K=512 INNER=512
// ekv never materialized. R6: qe + out-proj folded INTO attn (per-head proj
// partials, gate_ln sums 8 + bout2), ff1 split-K x2 w/ gelu in ff2 A-stage,
// nodes-copy folded into ln. 19 dispatches total.

#define DEV __device__ __forceinline__

constexpr int Bn = 4, Nn = 128, DIMn = 256, HEADSn = 8, DHn = 64, EDGEn = 64,
              DEPTHn = 2, Kn = 512, INNERn = 512;
constexpr int QKVW = 1536;
constexpr int PART = 131072;  // stride of proj partial buffers (floats)

DEV float wave_reduce_sum(float v) {
#pragma unroll
  for (int m = 32; m >= 1; m >>= 1) v += __shfl_xor(v, m);
  return v;
}

DEV float block_reduce_sum_256(float v, float* red) {
  v = wave_reduce_sum(v);
  int tid = threadIdx.x;
  if ((tid & 63) == 0) red[tid >> 6] = v;
  __syncthreads();
  v = red[0] + red[1] + red[2] + red[3];
  __syncthreads();
  return v;
}

DEV float gelu_exact(float x) {
  return 0.5f * x * (1.f + erff(x * 0.70710678118654752f));
}

// ---------------------------------------------------------------------------
// Edge LayerNorm -> e[b][i][c][j]  AND  eT[b][i][j][c]. Block per (b,i).
__global__ __launch_bounds__(128) void edge_ln_kernel(
    const float* __restrict__ edges, const float* __restrict__ g,
    const float* __restrict__ bta, float* __restrict__ e,
    float* __restrict__ eT) {
  __shared__ float ets[128 * 65];
  int blk = blockIdx.x;
  int i = blk & 127, b = blk >> 7;
  int j = threadIdx.x;
  const float* src = edges + (size_t)b * EDGEn * Nn * Nn + i * Nn + j;
  float vals[EDGEn];
  float s = 0.f;
#pragma unroll
  for (int c = 0; c < EDGEn; ++c) {
    float x = src[(size_t)c * (Nn * Nn)];
    vals[c] = x;
    s += x;
  }
  float m = s * (1.0f / 64.0f);
  float s2 = 0.f;
#pragma unroll
  for (int c = 0; c < EDGEn; ++c) {
    float d = vals[c] - m;
    s2 += d * d;
  }
  float inv = 1.f / sqrtf(s2 * (1.0f / 64.0f) + 1e-5f);
  float* dst = e + ((size_t)(b * Nn + i) * EDGEn) * Nn + j;
#pragma unroll
  for (int c = 0; c < EDGEn; ++c) {
    float o = (vals[c] - m) * inv * g[c] + bta[c];
    dst[(size_t)c * Nn] = o;
    ets[j * 65 + c] = o;
  }
  __syncthreads();
  float* dstT = eT + ((size_t)(b * Nn + i) * Nn) * EDGEn;
#pragma unroll
  for (int it = 0; it < 16; ++it) {
    int f4 = it * 128 + j;
    int jj = f4 >> 4, c4 = (f4 & 15) << 2;
    float4 o4 = {ets[jj * 65 + c4], ets[jj * 65 + c4 + 1],
                 ets[jj * 65 + c4 + 2], ets[jj * 65 + c4 + 3]};
    *(float4*)(dstT + (size_t)jj * EDGEn + c4) = o4;
  }
}

// ---------------------------------------------------------------------------
__global__ void rope_table_kernel(float* __restrict__ cost,
                                  float* __restrict__ sint) {
  int t = blockIdx.x * 256 + threadIdx.x;
  if (t >= Nn * 32) return;
  int n = t >> 5, p = t & 31;
  float inv = powf(10000.f, -(float)(2 * p) / 64.f);
  float fr = (float)n * inv;
  cost[t] = cosf(fr);
  sint[t] = sinf(fr);
}

// ---------------------------------------------------------------------------
// Fold kernel: W2[l][h*64+c][n] = sum_d wek[l][c][h64+d] * w_out[l][h64+d][n]
// and b_out2[l][n] = b_out[l][n] + sum_k bek[l][k]*w_out[l][k][n].
__global__ __launch_bounds__(256) void wfold_kernel(
    const float* __restrict__ wek, const float* __restrict__ w_out,
    const float* __restrict__ bek, const float* __restrict__ b_out,
    float* __restrict__ W2, float* __restrict__ b_out2) {
  int blk = blockIdx.x;
  int tid = threadIdx.x;
  if (blk < 64) {
    int l = blk >> 5, h = (blk >> 2) & 7, nt = blk & 3;
    __shared__ float As[64 * 65];
    __shared__ float Bs[64 * 68];
    const float* wekl = wek + (size_t)l * 64 * 512 + h * 64;
    const float* woutl =
        w_out + (size_t)l * 512 * 256 + (size_t)(h * 64) * 256 + nt * 64;
    for (int f = tid; f < 1024; f += 256) {
      int c = f >> 4, d4 = (f & 15) << 2;
      float4 w4 = *(const float4*)(wekl + (size_t)c * 512 + d4);
      As[c * 65 + d4 + 0] = w4.x;
      As[c * 65 + d4 + 1] = w4.y;
      As[c * 65 + d4 + 2] = w4.z;
      As[c * 65 + d4 + 3] = w4.w;
    }
    for (int f = tid; f < 1024; f += 256) {
      int d = f >> 4, n4 = (f & 15) << 2;
      float4 w4 = *(const float4*)(woutl + (size_t)d * 256 + n4);
      Bs[d * 68 + n4 + 0] = w4.x;
      Bs[d * 68 + n4 + 1] = w4.y;
      Bs[d * 68 + n4 + 2] = w4.z;
      Bs[d * 68 + n4 + 3] = w4.w;
    }
    __syncthreads();
    int tx = tid & 15, ty = tid >> 4;
    float acc[4][4] = {};
    for (int d = 0; d < 64; ++d) {
      float4 bv = *(const float4*)&Bs[d * 68 + tx * 4];
#pragma unroll
      for (int u = 0; u < 4; ++u) {
        float a = As[(ty * 4 + u) * 65 + d];
        acc[u][0] += a * bv.x;
        acc[u][1] += a * bv.y;
        acc[u][2] += a * bv.z;
        acc[u][3] += a * bv.w;
      }
    }
#pragma unroll
    for (int u = 0; u < 4; ++u) {
      float4 o = {acc[u][0], acc[u][1], acc[u][2], acc[u][3]};
      *(float4*)(W2 + (size_t)l * 512 * 256 +
                 (size_t)(h * 64 + ty * 4 + u) * 256 + nt * 64 + tx * 4) = o;
    }
  } else {
    int t = blk - 64;
    int l = t >> 2, nt = t & 3;
    __shared__ float part[256];
    int nn = tid & 63, kq = tid >> 6;
    const float* wcol = w_out + (size_t)l * 512 * 256 + nt * 64 + nn;
    float acc = 0.f;
    for (int k = kq * 128; k < kq * 128 + 128; ++k)
      acc += bek[l * 512 + k] * wcol[(size_t)k * 256];
    part[tid] = acc;
    __syncthreads();
    if (tid < 64)
      b_out2[l * 256 + nt * 64 + nn] =
          b_out[l * 256 + nt * 64 + nn] + part[nn] + part[64 + nn] +
          part[128 + nn] + part[192 + nn];
  }
}

// ---------------------------------------------------------------------------
// Row LayerNorm over DIM=256; also copies x into nodes (layer-0 entry only).
__global__ __launch_bounds__(256) void ln_kernel(const float* __restrict__ x,
                                                 const float* __restrict__ g,
                                                 const float* __restrict__ b,
                                                 float* __restrict__ y,
                                                 float* __restrict__ nodes) {
  __shared__ float red[4];
  int row = blockIdx.x, tid = threadIdx.x;
  float v = x[(size_t)row * DIMn + tid];
  nodes[(size_t)row * DIMn + tid] = v;
  float m = block_reduce_sum_256(v, red) * (1.0f / 256.0f);
  float d = v - m;
  float var = block_reduce_sum_256(d * d, red) * (1.0f / 256.0f);
  float inv = 1.f / sqrtf(var + 1e-5f);
  y[(size_t)row * DIMn + tid] = d * inv * g[tid] + b[tid];
}

// ---------------------------------------------------------------------------
// fp32 GEMM, 32x64 tile, BK=32, 2x4 microtile, register double-buffered.
// A2: A-stage sums two partials; aact==1: gelu after the sum.
// Dual-N (W2n at col>=N1), dual-K (k>=Ksplit reads Wkb), split-K via z.
// act: 0 none, 1 exact gelu, 4 qkv mode (rope cols<1024; k section -> kT).
__global__ __launch_bounds__(256) void gemm_kernel(
    const float* __restrict__ A, const float* __restrict__ A2, int aact,
    const float* __restrict__ W1, int N1, const float* __restrict__ b1,
    const float* __restrict__ W2n, int N2, const float* __restrict__ b2,
    const float* __restrict__ Wkb, int Ksplit, float* __restrict__ C, int M,
    int Ntot, int K, int kspan, int act, const float* __restrict__ cost,
    const float* __restrict__ sint, float* __restrict__ kT) {
  __shared__ float As[32][34];
  __shared__ __align__(16) float Bs[32][68];
  int tid = threadIdx.x;
  int bx = blockIdx.x, by = blockIdx.y, zid = blockIdx.z;
  int tx = tid & 15, ty = tid >> 4;
  int arow = tid >> 3, acol = (tid & 7) << 2;
  int brow = tid >> 4, bcol = (tid & 15) << 2;
  int col0 = bx * 64;
  const float* W = W1;
  const float* bias = b1;
  int Nw = N1, wcol = col0;
  if (W2n && col0 >= N1) {
    W = W2n;
    bias = b2;
    Nw = N2;
    wcol = col0 - N1;
  }
  int kb = zid * kspan, kend = kb + kspan;
  const float* arp = A + (size_t)(by * 32 + arow) * K;
  const float* arp2 = A2 ? A2 + (size_t)(by * 32 + arow) * K : nullptr;

  auto load_a = [&](int kpos) -> float4 {
    float4 a = *(const float4*)(arp + kpos + acol);
    if (arp2) {
      float4 a2 = *(const float4*)(arp2 + kpos + acol);
      a.x += a2.x;
      a.y += a2.y;
      a.z += a2.z;
      a.w += a2.w;
    }
    if (aact == 1) {
      a.x = gelu_exact(a.x);
      a.y = gelu_exact(a.y);
      a.z = gelu_exact(a.z);
      a.w = gelu_exact(a.w);
    }
    return a;
  };

  float4 a_nxt = load_a(kb);
  const float* w0p;
  const float* w1p;
  {
    int kr0 = kb + brow, kr1 = kb + brow + 16;
    w0p = (Ksplit && kr0 >= Ksplit)
              ? Wkb + (size_t)(kr0 - Ksplit) * Nw + wcol + bcol
              : W + (size_t)kr0 * Nw + wcol + bcol;
    w1p = (Ksplit && kr1 >= Ksplit)
              ? Wkb + (size_t)(kr1 - Ksplit) * Nw + wcol + bcol
              : W + (size_t)kr1 * Nw + wcol + bcol;
  }
  float4 b0_nxt = *(const float4*)w0p;
  float4 b1_nxt = *(const float4*)w1p;

  float acc[2][4] = {};
  for (int k0 = kb; k0 < kend; k0 += 32) {
    As[acol + 0][arow] = a_nxt.x;
    As[acol + 1][arow] = a_nxt.y;
    As[acol + 2][arow] = a_nxt.z;
    As[acol + 3][arow] = a_nxt.w;
    *(float4*)&Bs[brow][bcol] = b0_nxt;
    *(float4*)&Bs[brow + 16][bcol] = b1_nxt;
    __syncthreads();
    int kn = k0 + 32;
    if (kn < kend) {
      a_nxt = load_a(kn);
      int kr0 = kn + brow, kr1 = kn + brow + 16;
      w0p = (Ksplit && kr0 >= Ksplit)
                ? Wkb + (size_t)(kr0 - Ksplit) * Nw + wcol + bcol
                : W + (size_t)kr0 * Nw + wcol + bcol;
      w1p = (Ksplit && kr1 >= Ksplit)
                ? Wkb + (size_t)(kr1 - Ksplit) * Nw + wcol + bcol
                : W + (size_t)kr1 * Nw + wcol + bcol;
      b0_nxt = *(const float4*)w0p;
      b1_nxt = *(const float4*)w1p;
    }
#pragma unroll
    for (int kk = 0; kk < 32; ++kk) {
      float2 av = *(const float2*)&As[kk][ty * 2];
      float4 bv = *(const float4*)&Bs[kk][tx * 4];
      acc[0][0] += av.x * bv.x;
      acc[0][1] += av.x * bv.y;
      acc[0][2] += av.x * bv.z;
      acc[0][3] += av.x * bv.w;
      acc[1][0] += av.y * bv.x;
      acc[1][1] += av.y * bv.y;
      acc[1][2] += av.y * bv.z;
      acc[1][3] += av.y * bv.w;
    }
    __syncthreads();
  }
  int ccol = wcol + tx * 4;
  bool ksec = (act == 4) && (col0 >= 512) && (col0 < 1024);
  float* trans = (float*)Bs;
  float* Cz = C + (size_t)zid * M * Ntot;
#pragma unroll
  for (int u = 0; u < 2; ++u) {
    int r = by * 32 + ty * 2 + u;
    float o[4];
#pragma unroll
    for (int w = 0; w < 4; ++w)
      o[w] = acc[u][w] + (zid == 0 ? bias[ccol + w] : 0.f);
    if (act == 1) {
#pragma unroll
      for (int w = 0; w < 4; ++w) o[w] = gelu_exact(o[w]);
    } else if (act == 4 && col0 < 1024) {
      int n = r & 127;
      int p0 = (ccol & 63) >> 1;
      float c0 = cost[n * 32 + p0], s0 = sint[n * 32 + p0];
      float c1 = cost[n * 32 + p0 + 1], s1 = sint[n * 32 + p0 + 1];
      float x0 = o[0], x1 = o[1], x2 = o[2], x3 = o[3];
      o[0] = x0 * c0 - x1 * s0;
      o[1] = x1 * c0 + x0 * s0;
      o[2] = x2 * c1 - x3 * s1;
      o[3] = x3 * c1 + x2 * s1;
    }
    if (ksec) {
      int jl = ty * 2 + u;
#pragma unroll
      for (int w = 0; w < 4; ++w) trans[(tx * 4 + w) * 33 + jl] = o[w];
    } else {
      float4 o4 = {o[0], o[1], o[2], o[3]};
      *(float4*)(Cz + (size_t)r * Ntot + col0 + tx * 4) = o4;
    }
  }
  if (ksec) {
    __syncthreads();
    int h = (col0 - 512) >> 6;
    int bb = (by * 32) >> 7;
#pragma unroll
    for (int q = 0; q < 2; ++q) {
      int f4 = tid * 2 + q;
      int dl = f4 >> 3, j4 = (f4 & 7) << 2;
      int jj = (by * 32 + j4) & 127;
      float4 o4 = {trans[dl * 33 + j4], trans[dl * 33 + j4 + 1],
                   trans[dl * 33 + j4 + 2], trans[dl * 33 + j4 + 3]};
      *(float4*)(kT + ((size_t)(bb * 8 + h) * 64 + dl) * 128 + jj) = o4;
    }
  }
}

// ---------------------------------------------------------------------------
// Attention + qe + out-proj partial. Block per (b,h,i-quad), 128 threads.
// Writes per-head proj partial: proj[h*PART + row*256 + n].
__global__ __launch_bounds__(128) void attn_kernel(
    const float* __restrict__ qkv, const float* __restrict__ e,
    const float* __restrict__ eT, const float* __restrict__ kT,
    const float* __restrict__ wek, const float* __restrict__ w_out,
    const float* __restrict__ W2, float* __restrict__ proj) {
  __shared__ __align__(16) float qs[256];
  __shared__ __align__(16) float qes[256];
  __shared__ __align__(16) float att[512];  // reused as pav after P3
  __shared__ float avh[512];
  __shared__ float aeh[512];
  __shared__ float wekh[64 * 65];
  int blk = blockIdx.x;
  int iq = blk & 31;
  int bh = blk >> 5;
  int h = bh & 7, b = bh >> 3;
  int i0 = iq * 4;
  int row0 = b * 128 + i0;
  int tid = threadIdx.x;

  // P0: stage rotated q (4 rows) + wek_h (64x64)
  for (int f = tid; f < 256; f += 128) {
    int ii = f >> 6, d = f & 63;
    qs[f] = qkv[(size_t)(row0 + ii) * QKVW + h * 64 + d];
  }
  for (int f = tid; f < 4096; f += 128) {
    int c = f >> 6, d = f & 63;
    wekh[c * 65 + d] = wek[(size_t)c * INNERn + h * 64 + d];
  }
  __syncthreads();

  // P0b: qe[ii][c] = sum_d qs[ii*64+d] * wekh[c][d]
  for (int f = tid; f < 256; f += 128) {
    int ii = f >> 6, c = f & 63;
    float acc = 0.f;
#pragma unroll
    for (int d = 0; d < 64; ++d) acc += qs[ii * 64 + d] * wekh[c * 65 + d];
    qes[f] = acc;
  }
  __syncthreads();

  // P1: sim. thread = (i2 = tid>>5, j-quad = tid&31)
  int i2 = tid >> 5, j4 = tid & 31;
  float s0 = 0.f, s1 = 0.f, s2 = 0.f, s3 = 0.f;
  {
    const float* ktb = kT + ((size_t)bh * 64) * 128 + j4 * 4;
#pragma unroll
    for (int d4 = 0; d4 < 64; d4 += 4) {
      float4 q4 = *(const float4*)&qs[i2 * 64 + d4];
      float4 k0 = *(const float4*)(ktb + (size_t)(d4 + 0) * 128);
      float4 k1 = *(const float4*)(ktb + (size_t)(d4 + 1) * 128);
      float4 k2 = *(const float4*)(ktb + (size_t)(d4 + 2) * 128);
      float4 k3 = *(const float4*)(ktb + (size_t)(d4 + 3) * 128);
      s0 += q4.x * k0.x + q4.y * k1.x + q4.z * k2.x + q4.w * k3.x;
      s1 += q4.x * k0.y + q4.y * k1.y + q4.z * k2.y + q4.w * k3.y;
      s2 += q4.x * k0.z + q4.y * k1.z + q4.z * k2.z + q4.w * k3.z;
      s3 += q4.x * k0.w + q4.y * k1.w + q4.z * k2.w + q4.w * k3.w;
    }
    const float* eb = e + ((size_t)(row0 + i2) * 64) * 128 + j4 * 4;
#pragma unroll
    for (int c4 = 0; c4 < 64; c4 += 4) {
      float4 qe4 = *(const float4*)&qes[i2 * 64 + c4];
      float4 e0 = *(const float4*)(eb + (size_t)(c4 + 0) * 128);
      float4 e1 = *(const float4*)(eb + (size_t)(c4 + 1) * 128);
      float4 e2 = *(const float4*)(eb + (size_t)(c4 + 2) * 128);
      float4 e3 = *(const float4*)(eb + (size_t)(c4 + 3) * 128);
      s0 += qe4.x * e0.x + qe4.y * e1.x + qe4.z * e2.x + qe4.w * e3.x;
      s1 += qe4.x * e0.y + qe4.y * e1.y + qe4.z * e2.y + qe4.w * e3.y;
      s2 += qe4.x * e0.z + qe4.y * e1.z + qe4.z * e2.z + qe4.w * e3.z;
      s3 += qe4.x * e0.w + qe4.y * e1.w + qe4.z * e2.w + qe4.w * e3.w;
    }
    s0 *= 0.125f;
    s1 *= 0.125f;
    s2 *= 0.125f;
    s3 *= 0.125f;
  }
  // P2: softmax within 32-lane group (each group owns one i')
  {
    float mx = fmaxf(fmaxf(s0, s1), fmaxf(s2, s3));
#pragma unroll
    for (int m = 16; m >= 1; m >>= 1) mx = fmaxf(mx, __shfl_xor(mx, m));
    float p0 = expf(s0 - mx), p1 = expf(s1 - mx), p2 = expf(s2 - mx),
          p3 = expf(s3 - mx);
    float sm = p0 + p1 + p2 + p3;
#pragma unroll
    for (int m = 16; m >= 1; m >>= 1) sm += __shfl_xor(sm, m);
    float inv = 1.f / sm;
    float4 a4 = {p0 * inv, p1 * inv, p2 * inv, p3 * inv};
    *(float4*)&att[i2 * 128 + j4 * 4] = a4;
  }
  __syncthreads();

  // P3: av[i'][d], ae[i'][c]
  {
    int d = tid & 63, half = tid >> 6;
    float av0 = 0.f, av1 = 0.f, av2 = 0.f, av3 = 0.f;
    float ae0 = 0.f, ae1 = 0.f, ae2 = 0.f, ae3 = 0.f;
    const float* vb = qkv + (size_t)(b * 128) * QKVW + 1024 + h * 64 + d;
    const float* etb = eT + ((size_t)row0 * 128) * 64 + d;
    for (int jq = 0; jq < 16; ++jq) {
      int jb = half * 64 + jq * 4;
      float4 a0 = *(const float4*)&att[0 * 128 + jb];
      float4 a1 = *(const float4*)&att[1 * 128 + jb];
      float4 a2 = *(const float4*)&att[2 * 128 + jb];
      float4 a3 = *(const float4*)&att[3 * 128 + jb];
#pragma unroll
      for (int t = 0; t < 4; ++t) {
        int j = jb + t;
        float vv = vb[(size_t)j * QKVW];
        float at0 = ((const float*)&a0)[t];
        float at1 = ((const float*)&a1)[t];
        float at2 = ((const float*)&a2)[t];
        float at3 = ((const float*)&a3)[t];
        av0 += at0 * vv;
        av1 += at1 * vv;
        av2 += at2 * vv;
        av3 += at3 * vv;
        float e0 = etb[(size_t)j * 64];
        float e1 = etb[8192 + (size_t)j * 64];
        float e2 = etb[16384 + (size_t)j * 64];
        float e3 = etb[24576 + (size_t)j * 64];
        ae0 += at0 * e0;
        ae1 += at1 * e1;
        ae2 += at2 * e2;
        ae3 += at3 * e3;
      }
    }
    avh[half * 256 + 0 * 64 + d] = av0;
    avh[half * 256 + 1 * 64 + d] = av1;
    avh[half * 256 + 2 * 64 + d] = av2;
    avh[half * 256 + 3 * 64 + d] = av3;
    aeh[half * 256 + 0 * 64 + d] = ae0;
    aeh[half * 256 + 1 * 64 + d] = ae1;
    aeh[half * 256 + 2 * 64 + d] = ae2;
    aeh[half * 256 + 3 * 64 + d] = ae3;
  }
  __syncthreads();

  // P4a: combine halves into pav (reuse att): pav[ii][k] = [av(64)|ae(64)]
  for (int f = tid; f < 256; f += 128) {
    int ii = f >> 6, dd = f & 63;
    att[ii * 128 + dd] = avh[ii * 64 + dd] + avh[256 + ii * 64 + dd];
    att[ii * 128 + 64 + dd] = aeh[ii * 64 + dd] + aeh[256 + ii * 64 + dd];
  }
  __syncthreads();

  // P4b: out-proj partial for this head. thread = (rp = tid>>6, n4 = (tid&63)*4)
  // rows r = rp*2 + u; out[r][n] = sum_k pav[r][k] * Wcat[k][n]
  {
    int rp = tid >> 6, n4 = (tid & 63) << 2;
    int r0 = rp * 2, r1 = rp * 2 + 1;
    float o0[4] = {}, o1[4] = {};
    const float* wo = w_out + (size_t)(h * 64) * 256 + n4;
#pragma unroll 8
    for (int k = 0; k < 64; ++k) {
      float4 w4 = *(const float4*)(wo + (size_t)k * 256);
      float a0 = att[r0 * 128 + k];
      float a1 = att[r1 * 128 + k];
      o0[0] += a0 * w4.x;
      o0[1] += a0 * w4.y;
      o0[2] += a0 * w4.z;
      o0[3] += a0 * w4.w;
      o1[0] += a1 * w4.x;
      o1[1] += a1 * w4.y;
      o1[2] += a1 * w4.z;
      o1[3] += a1 * w4.w;
    }
    const float* w2 = W2 + (size_t)(h * 64) * 256 + n4;
#pragma unroll 8
    for (int k = 0; k < 64; ++k) {
      float4 w4 = *(const float4*)(w2 + (size_t)k * 256);
      float a0 = att[r0 * 128 + 64 + k];
      float a1 = att[r1 * 128 + 64 + k];
      o0[0] += a0 * w4.x;
      o0[1] += a0 * w4.y;
      o0[2] += a0 * w4.z;
      o0[3] += a0 * w4.w;
      o1[0] += a1 * w4.x;
      o1[1] += a1 * w4.y;
      o1[2] += a1 * w4.z;
      o1[3] += a1 * w4.w;
    }
    float* pp = proj + (size_t)h * PART;
    float4 v0 = {o0[0], o0[1], o0[2], o0[3]};
    float4 v1 = {o1[0], o1[1], o1[2], o1[3]};
    *(float4*)(pp + (size_t)(row0 + r0) * 256 + n4) = v0;
    *(float4*)(pp + (size_t)(row0 + r1) * 256 + n4) = v1;
  }
}

// ---------------------------------------------------------------------------
// Gated residual + optional fused LN. x = sum of nparts partials (+ badd).
__global__ __launch_bounds__(256) void gate_ln_kernel(
    const float* __restrict__ x, int nparts, const float* __restrict__ badd,
    float* __restrict__ nodes, const float* __restrict__ gw,
    const float* __restrict__ lng, const float* __restrict__ lnb,
    float* __restrict__ xln) {
  __shared__ float red[4];
  int row = blockIdx.x, tid = threadIdx.x;
  size_t off = (size_t)row * DIMn + tid;
  float xv = x[off];
  for (int p = 1; p < nparts; ++p) xv += x[off + (size_t)p * PART];
  if (badd) xv += badd[tid];
  float rv = nodes[off];
  float pv =
      xv * gw[tid] + rv * gw[DIMn + tid] + (xv - rv) * gw[2 * DIMn + tid];
  float ssum = block_reduce_sum_256(pv, red);
  float gsig = 1.f / (1.f + expf(-ssum));
  float nv = xv * gsig + rv * (1.f - gsig);
  nodes[off] = nv;
  if (lng) {
    float m = block_reduce_sum_256(nv, red) * (1.0f / 256.0f);
    float d = nv - m;
    float var = block_reduce_sum_256(d * d, red) * (1.0f / 256.0f);
    float inv = 1.f / sqrtf(var + 1e-5f);
    xln[off] = d * inv * lng[tid] + lnb[tid];
  }
}

// ---------------------------------------------------------------------------
// VQ nearest neighbor: thread-per-codebook-entry, 4 rows per block.
__global__ __launch_bounds__(256) void vq_kernel(
    const float* __restrict__ nodes, const float* __restrict__ codebook,
    float* __restrict__ out) {
  __shared__ __align__(16) float zs[4 * 256];
  __shared__ float wval[4][4];
  __shared__ int widx[4][4];
  __shared__ int fidx[4];
  int row0 = blockIdx.x * 4;
  int tid = threadIdx.x;
  for (int f = tid; f < 1024; f += 256) zs[f] = nodes[(size_t)row0 * DIMn + f];
  __syncthreads();
  int k1 = tid, k2 = tid + 256;
  const float4* c1p = (const float4*)(codebook + (size_t)k1 * DIMn);
  const float4* c2p = (const float4*)(codebook + (size_t)k2 * DIMn);
  float dot[4][2] = {};
  float cc0 = 0.f, cc1 = 0.f;
#pragma unroll 8
  for (int d4 = 0; d4 < 64; ++d4) {
    float4 c1 = c1p[d4], c2 = c2p[d4];
    cc0 += c1.x * c1.x + c1.y * c1.y + c1.z * c1.z + c1.w * c1.w;
    cc1 += c2.x * c2.x + c2.y * c2.y + c2.z * c2.z + c2.w * c2.w;
#pragma unroll
    for (int r = 0; r < 4; ++r) {
      float4 z = *(const float4*)&zs[r * 256 + d4 * 4];
      dot[r][0] += c1.x * z.x + c1.y * z.y + c1.z * z.z + c1.w * z.w;
      dot[r][1] += c2.x * z.x + c2.y * z.y + c2.z * z.z + c2.w * z.w;
    }
  }
  int lane = tid & 63, w = tid >> 6;
#pragma unroll
  for (int r = 0; r < 4; ++r) {
    float bv = cc0 - 2.f * dot[r][0];
    int bi = k1;
    float v2 = cc1 - 2.f * dot[r][1];
    if (v2 < bv) {
      bv = v2;
      bi = k2;
    }
#pragma unroll
    for (int m = 32; m >= 1; m >>= 1) {
      float ov = __shfl_xor(bv, m);
      int oi = __shfl_xor(bi, m);
      if (ov < bv || (ov == bv && oi < bi)) {
        bv = ov;
        bi = oi;
      }
    }
    if (lane == 0) {
      wval[r][w] = bv;
      widx[r][w] = bi;
    }
  }
  __syncthreads();
  if (tid < 4) {
    float bb = wval[tid][0];
    int bi = widx[tid][0];
    for (int t = 1; t < 4; ++t)
      if (wval[tid][t] < bb || (wval[tid][t] == bb && widx[tid][t] < bi)) {
        bb = wval[tid][t];
        bi = widx[tid][t];
      }
    fidx[tid] = bi;
  }
  __syncthreads();
  for (int f = tid; f < 1024; f += 256) {
    int r = f >> 8, d = f & 255;
    float zv = zs[f];
    float zq = codebook[(size_t)fidx[r] * DIMn + d];
    out[(size_t)(row0 + r) * DIMn + d] = zv + (zq - zv);
  }
}

// ---------------------------------------------------------------------------
extern "C" void kernel_launch(void* const* d_in, const int* in_sizes, int n_in,
                              void* d_out, int out_size, void* d_ws,
                              size_t ws_size, hipStream_t stream) {
  const float* nodes_in = (const float*)d_in[0];
  const float* edges = (const float*)d_in[1];
  const float* edge_ln_g = (const float*)d_in[2];
  const float* edge_ln_b = (const float*)d_in[3];
  const float* ln1_g = (const float*)d_in[4];
  const float* ln1_b = (const float*)d_in[5];
  const float* w_exp = (const float*)d_in[6];
  const float* b_exp = (const float*)d_in[7];
  const float* w_q = (const float*)d_in[8];
  const float* b_q = (const float*)d_in[9];
  const float* w_kv = (const float*)d_in[10];
  const float* b_kv = (const float*)d_in[11];
  const float* w_ekv = (const float*)d_in[12];
  const float* b_ekv = (const float*)d_in[13];
  const float* w_out = (const float*)d_in[14];
  const float* b_out = (const float*)d_in[15];
  const float* gate1_w = (const float*)d_in[16];
  const float* ln2_g = (const float*)d_in[17];
  const float* ln2_b = (const float*)d_in[18];
  const float* w_ff1 = (const float*)d_in[19];
  const float* b_ff1 = (const float*)d_in[20];
  const float* w_ff2 = (const float*)d_in[21];
  const float* b_ff2 = (const float*)d_in[22];
  const float* gate2_w = (const float*)d_in[23];
  const float* codebook = (const float*)d_in[24];

  float* ws = (float*)d_ws;
  float* e_buf = ws;                  // 4194304
  float* eT_buf = e_buf + 4194304;    // 4194304
  float* cost = eT_buf + 4194304;     // 4096
  float* sint = cost + 4096;          // 4096
  float* nodes = sint + 4096;         // 131072
  float* xln = nodes + 131072;        // 131072
  float* xe = xln + 131072;           // 524288 (2 split-K partials)
  float* qkvb = xe + 524288;          // 786432
  float* kTb = qkvb + 786432;         // 262144
  float* proj = kTb + 262144;         // 1048576 (8 per-head partials)
  float* ff1 = proj + 1048576;        // 1048576 (2 split-K partials)
  float* W2buf = ff1 + 1048576;       // 262144
  float* bout2 = W2buf + 262144;      // 512

  wfold_kernel<<<72, 256, 0, stream>>>(w_ekv, w_out, b_ekv, b_out, W2buf,
                                       bout2);
  edge_ln_kernel<<<512, 128, 0, stream>>>(edges, edge_ln_g, edge_ln_b, e_buf,
                                          eT_buf);
  rope_table_kernel<<<16, 256, 0, stream>>>(cost, sint);

  for (int l = 0; l < DEPTHn; ++l) {
    if (l == 0)
      ln_kernel<<<512, 256, 0, stream>>>(nodes_in, ln1_g, ln1_b, xln, nodes);
    // exp: split-K x2 -> xe partials
    gemm_kernel<<<dim3(8, 16, 2), 256, 0, stream>>>(
        xln, nullptr, 0, w_exp + l * 256 * 512, 512, b_exp + l * 512, nullptr,
        0, nullptr, nullptr, 0, xe, 512, 512, 256, 128, 0, cost, sint,
        nullptr);
    // fused q|kv (A = sum of 2 xe partials), rope epilogue + kT scatter
    gemm_kernel<<<dim3(24, 16, 1), 256, 0, stream>>>(
        xe, xe + 262144, 0, w_q + l * 512 * 512, 512, b_q + l * 512,
        w_kv + l * 512 * 1024, 1024, b_kv + l * 1024, nullptr, 0, qkvb, 512,
        QKVW, 512, 512, 4, cost, sint, kTb);
    // attention (+qe, +out-proj per-head partials)
    attn_kernel<<<1024, 128, 0, stream>>>(qkvb, e_buf, eT_buf, kTb,
                                          w_ekv + l * 64 * 512,
                                          w_out + l * 512 * 256,
                                          W2buf + l * 512 * 256, proj);
    gate_ln_kernel<<<512, 256, 0, stream>>>(
        proj, 8, bout2 + l * 256, nodes, gate1_w + l * 768, ln2_g + l * 256,
        ln2_b + l * 256, xln);
    // ff1: split-K x2 (gelu deferred to ff2 A-stage)
    gemm_kernel<<<dim3(16, 16, 2), 256, 0, stream>>>(
        xln, nullptr, 0, w_ff1 + l * 256 * 1024, 1024, b_ff1 + l * 1024,
        nullptr, 0, nullptr, nullptr, 0, ff1, 512, 1024, 256, 128, 0, cost,
        sint, nullptr);
    // ff2: A = gelu(ff1 p0 + p1), split-K x4 -> proj partials
    gemm_kernel<<<dim3(4, 16, 4), 256, 0, stream>>>(
        ff1, ff1 + 524288, 1, w_ff2 + l * 1024 * 256, 256, b_ff2 + l * 256,
        nullptr, 0, nullptr, nullptr, 0, proj, 512, 256, 1024, 256, 0, cost,
        sint, nullptr);
    const float* nlng = (l + 1 < DEPTHn) ? ln1_g + (l + 1) * 256 : nullptr;
    const float* nlnb = (l + 1 < DEPTHn) ? ln1_b + (l + 1) * 256 : nullptr;
    gate_ln_kernel<<<512, 256, 0, stream>>>(proj, 4, nullptr, nodes,
                                            gate2_w + l * 768, nlng, nlnb,
                                            xln);
  }
  vq_kernel<<<128, 256, 0, stream>>>(nodes, codebook, (float*)d_out);
}